// Round 1
// baseline (2122.922 us; speedup 1.0000x reference)
//
#include <hip/hip_runtime.h>
#include <stdint.h>

#define S_LEN 2048
#define D_DIM 7168
#define H_NUM 64
#define HD_DIM 128
#define QLR_DIM 1536
#define NQ_DIM 8192      // H*HD
#define ROPE_DIM 64
#define HALF_DIM 32
#define TOPK_N 512
#define NEG_INF_F (-1e30f)
#define LN_EPS 1e-6f
#define W_SCALE 0.011048543456039806f   // 1/sqrt(64*128)

#define KCHUNKS 7
#define KCHUNK_SZ 1024

// workspace layout (float offsets)
#define Q_OFF 0
#define K_OFF (S_LEN * NQ_DIM)                 // 16777216
#define W_OFF (K_OFF + S_LEN * HD_DIM)        // +262144
#define SC_OFF (W_OFF + S_LEN * H_NUM)        // +131072 ; scores S*S floats
// split-K partials (7*S*192 = 2.75M floats) alias the score region (4.19M floats)

// ---------------------------------------------------------------------------
// Kernel 1: Q = q_lora @ wq_b, fused interleaved RoPE on first 64 dims of each
// head. 128x128 tile, BK=8, 256 threads, 8x8 microtile.
// ---------------------------------------------------------------------------
__global__ __launch_bounds__(256) void qgemm_rope_kernel(
    const float* __restrict__ A,   // S x QLR
    const float* __restrict__ B,   // QLR x NQ
    const float* __restrict__ cosp, const float* __restrict__ sinp,
    float* __restrict__ Qo)        // S x NQ
{
    __shared__ float Ast[8][128];  // [k][m]
    __shared__ float Bs[8][128];   // [k][n]
    const int tid = threadIdx.x;
    const int tx = tid & 15, ty = tid >> 4;
    const int m0 = blockIdx.y * 128, n0 = blockIdx.x * 128;

    float acc[8][8];
#pragma unroll
    for (int i = 0; i < 8; i++)
#pragma unroll
        for (int j = 0; j < 8; j++) acc[i][j] = 0.f;

    const int arow = tid >> 1, ak = (tid & 1) * 4;
    const int brow = tid >> 5, bn = (tid & 31) * 4;
    const float* aptr = A + (size_t)(m0 + arow) * QLR_DIM + ak;
    const float* bptr = B + (size_t)brow * NQ_DIM + n0 + bn;

    for (int kt = 0; kt < QLR_DIM; kt += 8) {
        float4 av = *(const float4*)(aptr + kt);
        float4 bv = *(const float4*)(bptr + (size_t)kt * NQ_DIM);
        __syncthreads();
        Ast[ak + 0][arow] = av.x;
        Ast[ak + 1][arow] = av.y;
        Ast[ak + 2][arow] = av.z;
        Ast[ak + 3][arow] = av.w;
        *(float4*)&Bs[brow][bn] = bv;
        __syncthreads();
#pragma unroll
        for (int k = 0; k < 8; k++) {
            float4 a0 = *(const float4*)&Ast[k][ty * 4];
            float4 a1 = *(const float4*)&Ast[k][64 + ty * 4];
            float4 b0 = *(const float4*)&Bs[k][tx * 4];
            float4 b1 = *(const float4*)&Bs[k][64 + tx * 4];
            float a[8] = {a0.x, a0.y, a0.z, a0.w, a1.x, a1.y, a1.z, a1.w};
            float b[8] = {b0.x, b0.y, b0.z, b0.w, b1.x, b1.y, b1.z, b1.w};
#pragma unroll
            for (int i = 0; i < 8; i++)
#pragma unroll
                for (int j = 0; j < 8; j++)
                    acc[i][j] = fmaf(a[i], b[j], acc[i][j]);
        }
    }

    // Epilogue + RoPE. Col groups: {n0+tx*4..+3} (d=tx*4 in [0,63] -> rope),
    // {n0+64+tx*4..+3} (d>=64 -> passthrough).
#pragma unroll
    for (int i = 0; i < 8; i++) {
        int m = m0 + ((i < 4) ? (ty * 4 + i) : (64 + ty * 4 + (i - 4)));
        float o[8];
#pragma unroll
        for (int e = 0; e < 4; e += 2) {
            int jj = tx * 2 + (e >> 1);    // (tx*4+e)/2
            float c = cosp[m * HALF_DIM + jj];
            float sn = sinp[m * HALF_DIM + jj];
            float x1 = acc[i][e], x2 = acc[i][e + 1];
            o[e]     = x1 * c - x2 * sn;
            o[e + 1] = x1 * sn + x2 * c;
        }
        o[4] = acc[i][4]; o[5] = acc[i][5]; o[6] = acc[i][6]; o[7] = acc[i][7];
        float4 v0 = {o[0], o[1], o[2], o[3]};
        float4 v1 = {o[4], o[5], o[6], o[7]};
        *(float4*)&Qo[(size_t)m * NQ_DIM + n0 + tx * 4] = v0;
        *(float4*)&Qo[(size_t)m * NQ_DIM + n0 + 64 + tx * 4] = v1;
    }
}

// ---------------------------------------------------------------------------
// Kernel 2: split-K GEMM for ktmp = x@wk (cols 0..127) and w = x@wproj (cols
// 128..191). 64x64 tile, BK=16, 256 threads, 4x4 microtile. grid (32,3,7).
// ---------------------------------------------------------------------------
__global__ __launch_bounds__(256) void kw_gemm_kernel(
    const float* __restrict__ X, const float* __restrict__ WK,
    const float* __restrict__ WP, float* __restrict__ partial)
{
    __shared__ float Ast[16][64];  // [k][m]
    __shared__ float Bs[16][64];   // [k][n]
    const int tid = threadIdx.x;
    const int tx = tid & 15, ty = tid >> 4;
    const int m0 = blockIdx.x * 64;
    const int nt = blockIdx.y;
    const int kc = blockIdx.z;
    const float* Bp; int ldb, nbase;
    if (nt < 2) { Bp = WK; ldb = HD_DIM; nbase = nt * 64; }
    else        { Bp = WP; ldb = H_NUM; nbase = 0; }

    float acc[4][4];
#pragma unroll
    for (int i = 0; i < 4; i++)
#pragma unroll
        for (int j = 0; j < 4; j++) acc[i][j] = 0.f;

    const int arow = tid >> 2, ak = (tid & 3) * 4;
    const int brow = tid >> 4, bn = (tid & 15) * 4;
    const int kbeg = kc * KCHUNK_SZ;

    for (int kt = kbeg; kt < kbeg + KCHUNK_SZ; kt += 16) {
        float4 av = *(const float4*)&X[(size_t)(m0 + arow) * D_DIM + kt + ak];
        float4 bv = *(const float4*)&Bp[(size_t)(kt + brow) * ldb + nbase + bn];
        __syncthreads();
        Ast[ak + 0][arow] = av.x;
        Ast[ak + 1][arow] = av.y;
        Ast[ak + 2][arow] = av.z;
        Ast[ak + 3][arow] = av.w;
        *(float4*)&Bs[brow][bn] = bv;
        __syncthreads();
#pragma unroll
        for (int k = 0; k < 16; k++) {
            float4 a = *(const float4*)&Ast[k][ty * 4];
            float4 b = *(const float4*)&Bs[k][tx * 4];
            float aa[4] = {a.x, a.y, a.z, a.w};
            float bb[4] = {b.x, b.y, b.z, b.w};
#pragma unroll
            for (int i = 0; i < 4; i++)
#pragma unroll
                for (int j = 0; j < 4; j++)
                    acc[i][j] = fmaf(aa[i], bb[j], acc[i][j]);
        }
    }
    const int nc0 = nt * 64;
#pragma unroll
    for (int i = 0; i < 4; i++) {
        float4 v = {acc[i][0], acc[i][1], acc[i][2], acc[i][3]};
        *(float4*)&partial[((size_t)kc * S_LEN + m0 + ty * 4 + i) * 192 + nc0 + tx * 4] = v;
    }
}

__global__ __launch_bounds__(256) void kw_reduce_kernel(
    const float* __restrict__ partial, float* __restrict__ Ko, float* __restrict__ Wo)
{
    int g = blockIdx.x * 256 + threadIdx.x;   // < S*192
    int m = g / 192, n = g % 192;
    float s = 0.f;
#pragma unroll
    for (int c = 0; c < KCHUNKS; c++)
        s += partial[((size_t)c * S_LEN + m) * 192 + n];
    if (n < HD_DIM) Ko[(size_t)m * HD_DIM + n] = s;
    else            Wo[(size_t)m * H_NUM + (n - HD_DIM)] = s * W_SCALE;
}

// ---------------------------------------------------------------------------
// Kernel 3: per-row layernorm + interleaved RoPE on k, in place.
// ---------------------------------------------------------------------------
__global__ __launch_bounds__(128) void knorm_rope_kernel(
    float* __restrict__ Kb, const float* __restrict__ gw, const float* __restrict__ gb,
    const float* __restrict__ cosp, const float* __restrict__ sinp)
{
    __shared__ float red[128];
    __shared__ float sh[128];
    const int m = blockIdx.x, t = threadIdx.x;
    float v = Kb[(size_t)m * HD_DIM + t];
    red[t] = v; __syncthreads();
    for (int off = 64; off > 0; off >>= 1) {
        if (t < off) red[t] += red[t + off];
        __syncthreads();
    }
    float mu = red[0] * (1.f / HD_DIM);
    __syncthreads();
    float dv = v - mu;
    red[t] = dv * dv; __syncthreads();
    for (int off = 64; off > 0; off >>= 1) {
        if (t < off) red[t] += red[t + off];
        __syncthreads();
    }
    float var = red[0] * (1.f / HD_DIM);
    float rs = rsqrtf(var + LN_EPS);
    float kn = dv * rs * gw[t] + gb[t];
    sh[t] = kn; __syncthreads();
    float out;
    if (t < ROPE_DIM) {
        int jj = t >> 1;
        float c = cosp[m * HALF_DIM + jj], sn = sinp[m * HALF_DIM + jj];
        out = ((t & 1) == 0) ? (sh[t] * c - sh[t + 1] * sn)
                             : (sh[t - 1] * sn + sh[t] * c);
    } else {
        out = kn;
    }
    Kb[(size_t)m * HD_DIM + t] = out;
}

// ---------------------------------------------------------------------------
// Kernel 4: index_score[s,t] = sum_h relu(q[s,h,:]·k[t,:]) * w[s,h].
// Tile: 32 s-rows x 64 t-cols; k tile resident in LDS (pad 132 -> 2-way only),
// q slice restaged per head. Only causal tiles (t0 <= s0+31) launched; topk
// applies the t<=s mask itself so upper-triangle scores are never read.
// ---------------------------------------------------------------------------
__global__ __launch_bounds__(256) void attn_kernel(
    const float* __restrict__ Qi, const float* __restrict__ Ki,
    const float* __restrict__ Wi, float* __restrict__ SC)
{
    const int tt = blockIdx.x, ts = blockIdx.y;
    const int s0 = ts * 32, t0 = tt * 64;
    if (t0 > s0 + 31) return;
    __shared__ float kk[64][132];
    __shared__ float qh[32][132];
    const int tid = threadIdx.x;
    const int tx = tid & 15, ty = tid >> 4;

    for (int u = 0; u < 8; u++) {
        int idx = tid + u * 256;
        int r = idx >> 5, c4 = (idx & 31) << 2;
        *(float4*)&kk[r][c4] = *(const float4*)&Ki[(size_t)(t0 + r) * HD_DIM + c4];
    }

    const int si0 = ty, si1 = ty + 16;
    float acc[2][4];
#pragma unroll
    for (int i = 0; i < 2; i++)
#pragma unroll
        for (int j = 0; j < 4; j++) acc[i][j] = 0.f;

    for (int h = 0; h < H_NUM; h++) {
        __syncthreads();
        for (int u = 0; u < 4; u++) {
            int idx = tid + u * 256;
            int r = idx >> 5, c4 = (idx & 31) << 2;
            *(float4*)&qh[r][c4] =
                *(const float4*)&Qi[(size_t)(s0 + r) * NQ_DIM + h * HD_DIM + c4];
        }
        __syncthreads();
        float w0 = Wi[(size_t)(s0 + si0) * H_NUM + h];
        float w1 = Wi[(size_t)(s0 + si1) * H_NUM + h];
        float sc[2][4];
#pragma unroll
        for (int i = 0; i < 2; i++)
#pragma unroll
            for (int j = 0; j < 4; j++) sc[i][j] = 0.f;
#pragma unroll 8
        for (int d = 0; d < HD_DIM; d += 4) {
            float4 q0 = *(const float4*)&qh[si0][d];
            float4 q1 = *(const float4*)&qh[si1][d];
#pragma unroll
            for (int j = 0; j < 4; j++) {
                float4 kv = *(const float4*)&kk[tx + 16 * j][d];
                sc[0][j] += q0.x * kv.x + q0.y * kv.y + q0.z * kv.z + q0.w * kv.w;
                sc[1][j] += q1.x * kv.x + q1.y * kv.y + q1.z * kv.z + q1.w * kv.w;
            }
        }
#pragma unroll
        for (int j = 0; j < 4; j++) {
            acc[0][j] += fmaxf(sc[0][j], 0.f) * w0;
            acc[1][j] += fmaxf(sc[1][j], 0.f) * w1;
        }
    }
#pragma unroll
    for (int i = 0; i < 2; i++) {
        int srow = s0 + (i ? si1 : si0);
#pragma unroll
        for (int j = 0; j < 4; j++)
            SC[(size_t)srow * S_LEN + t0 + tx + 16 * j] = acc[i][j];
    }
}

// ---------------------------------------------------------------------------
// Kernel 5: per-row top-512 via full bitonic sort of 2048 packed u64 keys.
// Key = sortable-float(val) << 32 | (2047 - t): descending sort reproduces
// jax.lax.top_k ordering (value desc, index asc on ties).
// ---------------------------------------------------------------------------
__device__ __forceinline__ unsigned int fkey(float f) {
    unsigned int u = __float_as_uint(f);
    return (u & 0x80000000u) ? ~u : (u | 0x80000000u);
}
__device__ __forceinline__ float fdec(unsigned int k) {
    unsigned int u = (k & 0x80000000u) ? (k & 0x7FFFFFFFu) : ~k;
    return __uint_as_float(u);
}

__global__ __launch_bounds__(256) void topk_kernel(
    const float* __restrict__ SC, float* __restrict__ outv, float* __restrict__ outi)
{
    __shared__ unsigned long long key[S_LEN];
    const int s = blockIdx.x, tid = threadIdx.x;
    for (int t = tid; t < S_LEN; t += 256) {
        float v = (t <= s) ? SC[(size_t)s * S_LEN + t] : NEG_INF_F;
        key[t] = ((unsigned long long)fkey(v) << 32) |
                 (unsigned long long)(unsigned int)(S_LEN - 1 - t);
    }
    __syncthreads();
    for (int k2 = 2; k2 <= S_LEN; k2 <<= 1) {
        for (int j = k2 >> 1; j > 0; j >>= 1) {
            for (int p = tid; p < S_LEN / 2; p += 256) {
                int i = 2 * p - (p & (j - 1));
                int ix = i + j;
                unsigned long long a = key[i], b = key[ix];
                bool up = ((i & k2) == 0);
                bool sw = up ? (a < b) : (a > b);
                if (sw) { key[i] = b; key[ix] = a; }
            }
            __syncthreads();
        }
    }
    for (int i2 = tid; i2 < TOPK_N; i2 += 256) {
        unsigned long long kv = key[i2];
        outv[(size_t)s * TOPK_N + i2] = fdec((unsigned int)(kv >> 32));
        outi[(size_t)s * TOPK_N + i2] =
            (float)(S_LEN - 1 - (int)(kv & 0xFFFFFFFFu));
    }
}

// ---------------------------------------------------------------------------
extern "C" void kernel_launch(void* const* d_in, const int* in_sizes, int n_in,
                              void* d_out, int out_size, void* d_ws, size_t ws_size,
                              hipStream_t stream)
{
    (void)in_sizes; (void)n_in; (void)out_size; (void)ws_size;
    const float* x      = (const float*)d_in[0];
    const float* q_lora = (const float*)d_in[1];
    const float* wq_b   = (const float*)d_in[2];
    const float* wk     = (const float*)d_in[3];
    const float* wproj  = (const float*)d_in[4];
    const float* knw    = (const float*)d_in[5];
    const float* knb    = (const float*)d_in[6];
    const float* cosp   = (const float*)d_in[7];
    const float* sinp   = (const float*)d_in[8];

    float* ws = (float*)d_ws;
    float* Qb = ws + Q_OFF;
    float* Kb = ws + K_OFF;
    float* Wb = ws + W_OFF;
    float* SCb = ws + SC_OFF;
    float* partial = ws + SC_OFF;   // alias: consumed before SC is written

    float* outv = (float*)d_out;
    float* outi = outv + (size_t)S_LEN * TOPK_N;

    qgemm_rope_kernel<<<dim3(NQ_DIM / 128, S_LEN / 128), 256, 0, stream>>>(
        q_lora, wq_b, cosp, sinp, Qb);
    kw_gemm_kernel<<<dim3(S_LEN / 64, 3, KCHUNKS), 256, 0, stream>>>(
        x, wk, wproj, partial);
    kw_reduce_kernel<<<(S_LEN * 192) / 256, 256, 0, stream>>>(partial, Kb, Wb);
    knorm_rope_kernel<<<S_LEN, 128, 0, stream>>>(Kb, knw, knb, cosp, sinp);
    attn_kernel<<<dim3(S_LEN / 64, S_LEN / 32), 256, 0, stream>>>(Qb, Kb, Wb, SCb);
    topk_kernel<<<S_LEN, 256, 0, stream>>>(SCb, outv, outi);
}

// Round 2
// 1135.065 us; speedup vs baseline: 1.8703x; 1.8703x over previous
//
#include <hip/hip_runtime.h>
#include <stdint.h>

#define S_LEN 2048
#define D_DIM 7168
#define H_NUM 64
#define HD_DIM 128
#define QLR_DIM 1536
#define NQ_DIM 8192      // H*HD
#define ROPE_DIM 64
#define HALF_DIM 32
#define TOPK_N 512
#define NEG_INF_F (-1e30f)
#define LN_EPS 1e-6f
#define W_SCALE 0.011048543456039806f   // 1/sqrt(64*128)

#define KCHUNKS 7
#define KCHUNK_SZ 1024

// workspace layout (float offsets)
#define QBF_OFF 0                                   // S*NQ bf16 = 8388608 floats
#define KF_OFF  (S_LEN * NQ_DIM / 2)                // 8388608
#define KBF_OFF (KF_OFF + S_LEN * HD_DIM)           // +262144
#define WF_OFF  (KBF_OFF + S_LEN * HD_DIM / 2)      // +131072
#define SC_OFF  (WF_OFF + S_LEN * H_NUM)            // +131072 ; scores S*S fp32
// split-K partials (7*S*192 = 2.75M floats) alias the score region (4.19M)

typedef __attribute__((ext_vector_type(8))) short short8;
typedef __attribute__((ext_vector_type(4))) float floatx4;

__device__ __forceinline__ ushort f2bf(float f) {
    unsigned int u = __float_as_uint(f);
    u += 0x7FFFu + ((u >> 16) & 1u);   // round-to-nearest-even
    return (ushort)(u >> 16);
}

// ---------------------------------------------------------------------------
// Kernel 1: Q = q_lora @ wq_b, fused interleaved RoPE, emits bf16 Q in
// [h][s][d] layout (one head per 128-col block). 128x128 tile, BK=8.
// ---------------------------------------------------------------------------
__global__ __launch_bounds__(256) void qgemm_rope_kernel(
    const float* __restrict__ A,   // S x QLR
    const float* __restrict__ B,   // QLR x NQ
    const float* __restrict__ cosp, const float* __restrict__ sinp,
    ushort* __restrict__ Qo)       // bf16 [H][S][HD]
{
    __shared__ float Ast[8][128];  // [k][m]
    __shared__ float Bs[8][128];   // [k][n]
    const int tid = threadIdx.x;
    const int tx = tid & 15, ty = tid >> 4;
    const int m0 = blockIdx.y * 128, n0 = blockIdx.x * 128;
    const int h = blockIdx.x;      // 128 cols == exactly one head

    float acc[8][8];
#pragma unroll
    for (int i = 0; i < 8; i++)
#pragma unroll
        for (int j = 0; j < 8; j++) acc[i][j] = 0.f;

    const int arow = tid >> 1, ak = (tid & 1) * 4;
    const int brow = tid >> 5, bn = (tid & 31) * 4;
    const float* aptr = A + (size_t)(m0 + arow) * QLR_DIM + ak;
    const float* bptr = B + (size_t)brow * NQ_DIM + n0 + bn;

    for (int kt = 0; kt < QLR_DIM; kt += 8) {
        float4 av = *(const float4*)(aptr + kt);
        float4 bv = *(const float4*)(bptr + (size_t)kt * NQ_DIM);
        __syncthreads();
        Ast[ak + 0][arow] = av.x;
        Ast[ak + 1][arow] = av.y;
        Ast[ak + 2][arow] = av.z;
        Ast[ak + 3][arow] = av.w;
        *(float4*)&Bs[brow][bn] = bv;
        __syncthreads();
#pragma unroll
        for (int k = 0; k < 8; k++) {
            float4 a0 = *(const float4*)&Ast[k][ty * 4];
            float4 a1 = *(const float4*)&Ast[k][64 + ty * 4];
            float4 b0 = *(const float4*)&Bs[k][tx * 4];
            float4 b1 = *(const float4*)&Bs[k][64 + tx * 4];
            float a[8] = {a0.x, a0.y, a0.z, a0.w, a1.x, a1.y, a1.z, a1.w};
            float b[8] = {b0.x, b0.y, b0.z, b0.w, b1.x, b1.y, b1.z, b1.w};
#pragma unroll
            for (int i = 0; i < 8; i++)
#pragma unroll
                for (int j = 0; j < 8; j++)
                    acc[i][j] = fmaf(a[i], b[j], acc[i][j]);
        }
    }

    // Epilogue + RoPE. d = tx*4 (<64: rope) and d = 64+tx*4 (passthrough).
#pragma unroll
    for (int i = 0; i < 8; i++) {
        int m = m0 + ((i < 4) ? (ty * 4 + i) : (64 + ty * 4 + (i - 4)));
        float o[8];
#pragma unroll
        for (int e = 0; e < 4; e += 2) {
            int jj = tx * 2 + (e >> 1);
            float c = cosp[m * HALF_DIM + jj];
            float sn = sinp[m * HALF_DIM + jj];
            float x1 = acc[i][e], x2 = acc[i][e + 1];
            o[e]     = x1 * c - x2 * sn;
            o[e + 1] = x1 * sn + x2 * c;
        }
        o[4] = acc[i][4]; o[5] = acc[i][5]; o[6] = acc[i][6]; o[7] = acc[i][7];
        ushort4 v0 = make_ushort4(f2bf(o[0]), f2bf(o[1]), f2bf(o[2]), f2bf(o[3]));
        ushort4 v1 = make_ushort4(f2bf(o[4]), f2bf(o[5]), f2bf(o[6]), f2bf(o[7]));
        *(ushort4*)&Qo[((size_t)h * S_LEN + m) * HD_DIM + tx * 4] = v0;
        *(ushort4*)&Qo[((size_t)h * S_LEN + m) * HD_DIM + 64 + tx * 4] = v1;
    }
}

// ---------------------------------------------------------------------------
// Kernel 2: split-K GEMM for ktmp = x@wk (cols 0..127) and w = x@wproj (cols
// 128..191). 64x64 tile, BK=16. grid (32,3,7).
// ---------------------------------------------------------------------------
__global__ __launch_bounds__(256) void kw_gemm_kernel(
    const float* __restrict__ X, const float* __restrict__ WK,
    const float* __restrict__ WP, float* __restrict__ partial)
{
    __shared__ float Ast[16][64];
    __shared__ float Bs[16][64];
    const int tid = threadIdx.x;
    const int tx = tid & 15, ty = tid >> 4;
    const int m0 = blockIdx.x * 64;
    const int nt = blockIdx.y;
    const int kc = blockIdx.z;
    const float* Bp; int ldb, nbase;
    if (nt < 2) { Bp = WK; ldb = HD_DIM; nbase = nt * 64; }
    else        { Bp = WP; ldb = H_NUM; nbase = 0; }

    float acc[4][4];
#pragma unroll
    for (int i = 0; i < 4; i++)
#pragma unroll
        for (int j = 0; j < 4; j++) acc[i][j] = 0.f;

    const int arow = tid >> 2, ak = (tid & 3) * 4;
    const int brow = tid >> 4, bn = (tid & 15) * 4;
    const int kbeg = kc * KCHUNK_SZ;

    for (int kt = kbeg; kt < kbeg + KCHUNK_SZ; kt += 16) {
        float4 av = *(const float4*)&X[(size_t)(m0 + arow) * D_DIM + kt + ak];
        float4 bv = *(const float4*)&Bp[(size_t)(kt + brow) * ldb + nbase + bn];
        __syncthreads();
        Ast[ak + 0][arow] = av.x;
        Ast[ak + 1][arow] = av.y;
        Ast[ak + 2][arow] = av.z;
        Ast[ak + 3][arow] = av.w;
        *(float4*)&Bs[brow][bn] = bv;
        __syncthreads();
#pragma unroll
        for (int k = 0; k < 16; k++) {
            float4 a = *(const float4*)&Ast[k][ty * 4];
            float4 b = *(const float4*)&Bs[k][tx * 4];
            float aa[4] = {a.x, a.y, a.z, a.w};
            float bb[4] = {b.x, b.y, b.z, b.w};
#pragma unroll
            for (int i = 0; i < 4; i++)
#pragma unroll
                for (int j = 0; j < 4; j++)
                    acc[i][j] = fmaf(aa[i], bb[j], acc[i][j]);
        }
    }
    const int nc0 = nt * 64;
#pragma unroll
    for (int i = 0; i < 4; i++) {
        float4 v = {acc[i][0], acc[i][1], acc[i][2], acc[i][3]};
        *(float4*)&partial[((size_t)kc * S_LEN + m0 + ty * 4 + i) * 192 + nc0 + tx * 4] = v;
    }
}

__global__ __launch_bounds__(256) void kw_reduce_kernel(
    const float* __restrict__ partial, float* __restrict__ Ko, float* __restrict__ Wo)
{
    int g = blockIdx.x * 256 + threadIdx.x;   // < S*192
    int m = g / 192, n = g % 192;
    float s = 0.f;
#pragma unroll
    for (int c = 0; c < KCHUNKS; c++)
        s += partial[((size_t)c * S_LEN + m) * 192 + n];
    if (n < HD_DIM) Ko[(size_t)m * HD_DIM + n] = s;
    else            Wo[(size_t)m * H_NUM + (n - HD_DIM)] = s * W_SCALE;
}

// ---------------------------------------------------------------------------
// Kernel 3: per-row layernorm + interleaved RoPE on k; emits bf16 K.
// ---------------------------------------------------------------------------
__global__ __launch_bounds__(128) void knorm_rope_kernel(
    const float* __restrict__ Kf, const float* __restrict__ gw, const float* __restrict__ gb,
    const float* __restrict__ cosp, const float* __restrict__ sinp,
    ushort* __restrict__ Kbf)
{
    __shared__ float red[128];
    __shared__ float sh[128];
    const int m = blockIdx.x, t = threadIdx.x;
    float v = Kf[(size_t)m * HD_DIM + t];
    red[t] = v; __syncthreads();
    for (int off = 64; off > 0; off >>= 1) {
        if (t < off) red[t] += red[t + off];
        __syncthreads();
    }
    float mu = red[0] * (1.f / HD_DIM);
    __syncthreads();
    float dv = v - mu;
    red[t] = dv * dv; __syncthreads();
    for (int off = 64; off > 0; off >>= 1) {
        if (t < off) red[t] += red[t + off];
        __syncthreads();
    }
    float var = red[0] * (1.f / HD_DIM);
    float rs = rsqrtf(var + LN_EPS);
    float kn = dv * rs * gw[t] + gb[t];
    sh[t] = kn; __syncthreads();
    float out;
    if (t < ROPE_DIM) {
        int jj = t >> 1;
        float c = cosp[m * HALF_DIM + jj], sn = sinp[m * HALF_DIM + jj];
        out = ((t & 1) == 0) ? (sh[t] * c - sh[t + 1] * sn)
                             : (sh[t - 1] * sn + sh[t] * c);
    } else {
        out = kn;
    }
    Kbf[(size_t)m * HD_DIM + t] = f2bf(out);
}

// ---------------------------------------------------------------------------
// Kernel 4: index_score via bf16 MFMA. 64(s)x64(t) causal tiles, 528 blocks,
// 4 waves (each: 16 s-rows x 64 t-cols). K B-fragments live in registers for
// the whole block (k is a single 128-dim head); Q restaged per head.
// XOR-swizzled LDS (block-of-8 ^ row&15) -> conflict-free b128 reads/writes.
// ---------------------------------------------------------------------------
__global__ __launch_bounds__(256) void attn_mfma_kernel(
    const ushort* __restrict__ Qb,  // bf16 [H][S][HD]
    const ushort* __restrict__ Kb,  // bf16 [S][HD]
    const float* __restrict__ Wf,   // fp32 [S][H], pre-scaled
    float* __restrict__ SC)
{
    __shared__ ushort Ks[64 * 128];
    __shared__ ushort Qs[64 * 128];
    __shared__ float  Wsm[64 * 68];

    const int bidx = blockIdx.x;
    int ts = (int)((sqrtf(8.0f * bidx + 1.0f) - 1.0f) * 0.5f);
    while ((ts + 1) * (ts + 2) / 2 <= bidx) ts++;
    while (ts * (ts + 1) / 2 > bidx) ts--;
    const int tt = bidx - ts * (ts + 1) / 2;
    const int s0 = ts * 64, t0 = tt * 64;

    const int tid = threadIdx.x;
    const int lane = tid & 63;
    const int m = lane & 15;          // M/N index within 16x16 tile
    const int q = lane >> 4;          // quad
    const int strip = (tid >> 6) * 16;

    const int rb = tid >> 4;          // staging row base (0..15)
    const int wblk = ((tid & 15) ^ rb) * 8;

    // ---- stage K tile (bf16) + W tile (fp32) ----
    {
        const uint4* gk = (const uint4*)(Kb + (size_t)t0 * HD_DIM);
#pragma unroll
        for (int u = 0; u < 4; u++) {
            uint4 v = gk[tid + u * 256];
            *(uint4*)&Ks[(rb + u * 16) * 128 + wblk] = v;
        }
        const float4* gw = (const float4*)(Wf + (size_t)s0 * H_NUM);
#pragma unroll
        for (int u = 0; u < 4; u++) {
            int ch = tid + u * 256;
            float4 v = gw[ch];
            *(float4*)&Wsm[(ch >> 4) * 68 + (ch & 15) * 4] = v;
        }
    }
    __syncthreads();

    // ---- preload B fragments (whole K tile) into registers ----
    short8 bf[4][4];   // [t-tile][k-step]
#pragma unroll
    for (int tile = 0; tile < 4; tile++) {
        int row = tile * 16 + m;
#pragma unroll
        for (int ks = 0; ks < 4; ks++)
            bf[tile][ks] = *(const short8*)&Ks[row * 128 + (((ks << 2) + q) ^ m) * 8];
    }

    float acc[4][4];
#pragma unroll
    for (int tile = 0; tile < 4; tile++)
#pragma unroll
        for (int r = 0; r < 4; r++) acc[tile][r] = 0.f;

    for (int h = 0; h < H_NUM; h++) {
        // issue Q-tile loads first (latency overlaps previous compute drain)
        uint4 v[4];
        const uint4* gq = (const uint4*)(Qb + ((size_t)h * S_LEN + s0) * HD_DIM);
#pragma unroll
        for (int u = 0; u < 4; u++) v[u] = gq[tid + u * 256];
        __syncthreads();   // prior head's Qs reads done
#pragma unroll
        for (int u = 0; u < 4; u++)
            *(uint4*)&Qs[(rb + u * 16) * 128 + wblk] = v[u];
        __syncthreads();

        short8 af[4];
        const int arow = strip + m;
#pragma unroll
        for (int ks = 0; ks < 4; ks++)
            af[ks] = *(const short8*)&Qs[arow * 128 + (((ks << 2) + q) ^ m) * 8];
        float wv[4];
#pragma unroll
        for (int r = 0; r < 4; r++) wv[r] = Wsm[(strip + q * 4 + r) * 68 + h];

#pragma unroll
        for (int tile = 0; tile < 4; tile++) {
            floatx4 p = {0.f, 0.f, 0.f, 0.f};
#pragma unroll
            for (int ks = 0; ks < 4; ks++)
                p = __builtin_amdgcn_mfma_f32_16x16x32_bf16(af[ks], bf[tile][ks], p, 0, 0, 0);
#pragma unroll
            for (int r = 0; r < 4; r++)
                acc[tile][r] += fmaxf(p[r], 0.f) * wv[r];
        }
    }

#pragma unroll
    for (int tile = 0; tile < 4; tile++)
#pragma unroll
        for (int r = 0; r < 4; r++)
            SC[(size_t)(s0 + strip + q * 4 + r) * S_LEN + t0 + tile * 16 + m] =
                acc[tile][r];
}

// ---------------------------------------------------------------------------
// Kernel 5: per-row top-512 via bitonic sort of 2048 packed u64 keys.
// ---------------------------------------------------------------------------
__device__ __forceinline__ unsigned int fkey(float f) {
    unsigned int u = __float_as_uint(f);
    return (u & 0x80000000u) ? ~u : (u | 0x80000000u);
}
__device__ __forceinline__ float fdec(unsigned int k) {
    unsigned int u = (k & 0x80000000u) ? (k & 0x7FFFFFFFu) : ~k;
    return __uint_as_float(u);
}

__global__ __launch_bounds__(256) void topk_kernel(
    const float* __restrict__ SC, float* __restrict__ outv, float* __restrict__ outi)
{
    __shared__ unsigned long long key[S_LEN];
    const int s = blockIdx.x, tid = threadIdx.x;
    for (int t = tid; t < S_LEN; t += 256) {
        float v = (t <= s) ? SC[(size_t)s * S_LEN + t] : NEG_INF_F;
        key[t] = ((unsigned long long)fkey(v) << 32) |
                 (unsigned long long)(unsigned int)(S_LEN - 1 - t);
    }
    __syncthreads();
    for (int k2 = 2; k2 <= S_LEN; k2 <<= 1) {
        for (int j = k2 >> 1; j > 0; j >>= 1) {
            for (int p = tid; p < S_LEN / 2; p += 256) {
                int i = 2 * p - (p & (j - 1));
                int ix = i + j;
                unsigned long long a = key[i], b = key[ix];
                bool up = ((i & k2) == 0);
                bool sw = up ? (a < b) : (a > b);
                if (sw) { key[i] = b; key[ix] = a; }
            }
            __syncthreads();
        }
    }
    for (int i2 = tid; i2 < TOPK_N; i2 += 256) {
        unsigned long long kv = key[i2];
        outv[(size_t)s * TOPK_N + i2] = fdec((unsigned int)(kv >> 32));
        outi[(size_t)s * TOPK_N + i2] =
            (float)(S_LEN - 1 - (int)(kv & 0xFFFFFFFFu));
    }
}

// ---------------------------------------------------------------------------
extern "C" void kernel_launch(void* const* d_in, const int* in_sizes, int n_in,
                              void* d_out, int out_size, void* d_ws, size_t ws_size,
                              hipStream_t stream)
{
    (void)in_sizes; (void)n_in; (void)out_size; (void)ws_size;
    const float* x      = (const float*)d_in[0];
    const float* q_lora = (const float*)d_in[1];
    const float* wq_b   = (const float*)d_in[2];
    const float* wk     = (const float*)d_in[3];
    const float* wproj  = (const float*)d_in[4];
    const float* knw    = (const float*)d_in[5];
    const float* knb    = (const float*)d_in[6];
    const float* cosp   = (const float*)d_in[7];
    const float* sinp   = (const float*)d_in[8];

    float* ws = (float*)d_ws;
    ushort* Qbf = (ushort*)(ws + QBF_OFF);
    float*  Kf  = ws + KF_OFF;
    ushort* Kbf = (ushort*)(ws + KBF_OFF);
    float*  Wf  = ws + WF_OFF;
    float*  SCb = ws + SC_OFF;
    float*  partial = ws + SC_OFF;   // alias: consumed before SC is written

    float* outv = (float*)d_out;
    float* outi = outv + (size_t)S_LEN * TOPK_N;

    qgemm_rope_kernel<<<dim3(NQ_DIM / 128, S_LEN / 128), 256, 0, stream>>>(
        q_lora, wq_b, cosp, sinp, Qbf);
    kw_gemm_kernel<<<dim3(S_LEN / 64, 3, KCHUNKS), 256, 0, stream>>>(
        x, wk, wproj, partial);
    kw_reduce_kernel<<<(S_LEN * 192) / 256, 256, 0, stream>>>(partial, Kf, Wf);
    knorm_rope_kernel<<<S_LEN, 128, 0, stream>>>(Kf, knw, knb, cosp, sinp, Kbf);
    attn_mfma_kernel<<<528, 256, 0, stream>>>(Qbf, Kbf, Wf, SCb);
    topk_kernel<<<S_LEN, 256, 0, stream>>>(SCb, outv, outi);
}

// Round 3
// 622.019 us; speedup vs baseline: 3.4130x; 1.8248x over previous
//
#include <hip/hip_runtime.h>
#include <stdint.h>

#define S_LEN 2048
#define D_DIM 7168
#define H_NUM 64
#define HD_DIM 128
#define QLR_DIM 1536
#define NQ_DIM 8192      // H*HD
#define ROPE_DIM 64
#define HALF_DIM 32
#define TOPK_N 512
#define NEG_INF_F (-1e30f)
#define LN_EPS 1e-6f
#define W_SCALE 0.011048543456039806f   // 1/sqrt(64*128)

#define KCHUNKS 7
#define KCHUNK_SZ 1024

// workspace layout (float offsets)
#define QBF_OFF 0                                    // S*NQ bf16 = 8388608 floats
#define ALORA_OFF (QBF_OFF + S_LEN * NQ_DIM / 2)     // q_lora bf16: S*QLR/2
#define WT_OFF   (ALORA_OFF + S_LEN * QLR_DIM / 2)   // wq_b^T bf16: NQ*QLR/2
#define KF_OFF   (WT_OFF + NQ_DIM * QLR_DIM / 2)
#define KBF_OFF  (KF_OFF + S_LEN * HD_DIM)
#define WF_OFF   (KBF_OFF + S_LEN * HD_DIM / 2)
#define SC_OFF   (WF_OFF + S_LEN * H_NUM)            // scores S*S fp32
// split-K partials (7*S*192 = 2.75M floats) alias the score region (4.19M)

typedef __attribute__((ext_vector_type(8))) short short8;
typedef __attribute__((ext_vector_type(4))) float floatx4;

__device__ __forceinline__ ushort f2bf(float f) {
    unsigned int u = __float_as_uint(f);
    u += 0x7FFFu + ((u >> 16) & 1u);   // round-to-nearest-even
    return (ushort)(u >> 16);
}
__device__ __forceinline__ unsigned int pack2bf(float lo, float hi) {
    return (unsigned int)f2bf(lo) | ((unsigned int)f2bf(hi) << 16);
}

__device__ __forceinline__ void gld_lds16(const ushort* g, ushort* l) {
    __builtin_amdgcn_global_load_lds(
        (const __attribute__((address_space(1))) unsigned int*)g,
        (__attribute__((address_space(3))) unsigned int*)l, 16, 0, 0);
}

// ---------------------------------------------------------------------------
// Kernel 0a: cast q_lora fp32 -> bf16 [S][QLR]
// ---------------------------------------------------------------------------
__global__ __launch_bounds__(256) void cast_qlora_kernel(
    const float* __restrict__ in, ushort* __restrict__ out)
{
    int g = (blockIdx.x * 256 + threadIdx.x) * 8;
    float4 a = *(const float4*)&in[g];
    float4 b = *(const float4*)&in[g + 4];
    uint4 v;
    v.x = pack2bf(a.x, a.y); v.y = pack2bf(a.z, a.w);
    v.z = pack2bf(b.x, b.y); v.w = pack2bf(b.z, b.w);
    *(uint4*)&out[g] = v;
}

// ---------------------------------------------------------------------------
// Kernel 0b: transpose+cast wq_b fp32 [QLR][NQ] -> bf16 WT [NQ][QLR].
// 64x64 tiles through LDS (pitch 72 breaks pow2 stride).
// ---------------------------------------------------------------------------
__global__ __launch_bounds__(256) void transpose_wqb_kernel(
    const float* __restrict__ W, ushort* __restrict__ WT)
{
    __shared__ ushort tl[64][72];
    const int n0 = blockIdx.x * 64, k0 = blockIdx.y * 64;
    const int t = threadIdx.x;
    const int r = t >> 4, c4 = (t & 15) * 4;
#pragma unroll
    for (int u = 0; u < 4; u++) {
        int kk = r + u * 16;
        float4 v = *(const float4*)&W[(size_t)(k0 + kk) * NQ_DIM + n0 + c4];
        tl[c4 + 0][kk] = f2bf(v.x);
        tl[c4 + 1][kk] = f2bf(v.y);
        tl[c4 + 2][kk] = f2bf(v.z);
        tl[c4 + 3][kk] = f2bf(v.w);
    }
    __syncthreads();
#pragma unroll
    for (int u = 0; u < 2; u++) {
        int i = t + u * 256;             // 512 chunks of 16B
        int nr = i >> 3, c8 = (i & 7) * 8;
        uint4 v = *(const uint4*)&tl[nr][c8];
        *(uint4*)&WT[(size_t)(n0 + nr) * QLR_DIM + k0 + c8] = v;
    }
}

// ---------------------------------------------------------------------------
// Kernel 1: Q = q_lora @ wq_b via bf16 MFMA (m97 structure: 128x128 tile,
// BK=32, global_load_lds width=16, [row][k] LDS tiles, ds_read_b128 frags).
// Fused interleaved RoPE epilogue (cross-lane pair via shfl_xor), LDS-bounced
// coalesced bf16 store to [H][S][HD]. grid(64 n-blocks, 16 m-blocks):
// linear%8 = head%8 -> per-XCD L2-resident 3.1MB WT slice.
// ---------------------------------------------------------------------------
__global__ __launch_bounds__(256) void qgemm_mfma_kernel(
    const ushort* __restrict__ Abf,   // bf16 [S][QLR]
    const ushort* __restrict__ WT,    // bf16 [NQ][QLR]
    const float* __restrict__ cosp, const float* __restrict__ sinp,
    ushort* __restrict__ Qo)          // bf16 [H][S][HD]
{
    __shared__ ushort lds[128 * 136];          // 34,816 B; staging aliases front
    ushort* As = lds;                          // 128 rows x 32 bf16 (64B rows)
    ushort* Bs = lds + 4096;                   // 128 rows x 32 bf16

    const int tid = threadIdx.x;
    const int lane = tid & 63;
    const int wave = tid >> 6;
    const int m = lane & 15;
    const int q = lane >> 4;
    const int wm = wave & 1, wn = wave >> 1;
    const int m0 = blockIdx.y * 128;
    const int n0 = blockIdx.x * 128;
    const int h = blockIdx.x;                  // 128 cols == one head

    floatx4 acc[4][4];
#pragma unroll
    for (int i = 0; i < 4; i++)
#pragma unroll
        for (int j = 0; j < 4; j++) acc[i][j] = (floatx4){0.f, 0.f, 0.f, 0.f};

    // staging: per operand 512 slots of 16B; wave w issue u owns slots
    // [(u*4+w)*64 .. +63]; lane lands at ldsbase + lane*16.
    const ushort* agp[2];
    const ushort* bgp[2];
    unsigned int sbase[2];
#pragma unroll
    for (int u = 0; u < 2; u++) {
        int s = (u * 4 + wave) * 64 + lane;
        agp[u] = Abf + (size_t)(m0 + (s >> 2)) * QLR_DIM + (s & 3) * 8;
        bgp[u] = WT + (size_t)(n0 + (s >> 2)) * QLR_DIM + (s & 3) * 8;
        sbase[u] = (unsigned int)((u * 4 + wave) * 64 * 8);  // ushort offset
    }

    for (int kt = 0; kt < QLR_DIM; kt += 32) {
        __syncthreads();   // previous iteration's frag reads done
#pragma unroll
        for (int u = 0; u < 2; u++) gld_lds16(agp[u] + kt, &As[sbase[u]]);
#pragma unroll
        for (int u = 0; u < 2; u++) gld_lds16(bgp[u] + kt, &Bs[sbase[u]]);
        __syncthreads();   // vmcnt(0) drain -> tiles resident

        short8 af[4], bf[4];
#pragma unroll
        for (int mt = 0; mt < 4; mt++)
            af[mt] = *(const short8*)&As[(wm * 64 + mt * 16 + m) * 32 + q * 8];
#pragma unroll
        for (int nt = 0; nt < 4; nt++)
            bf[nt] = *(const short8*)&Bs[(wn * 64 + nt * 16 + m) * 32 + q * 8];
#pragma unroll
        for (int mt = 0; mt < 4; mt++)
#pragma unroll
            for (int nt = 0; nt < 4; nt++)
                acc[mt][nt] = __builtin_amdgcn_mfma_f32_16x16x32_bf16(
                    af[mt], bf[nt], acc[mt][nt], 0, 0, 0);
    }

    __syncthreads();   // all waves done reading As/Bs before ep overwrites
    ushort* ep = lds;  // 128 x (pitch 136) bf16

#pragma unroll
    for (int mt = 0; mt < 4; mt++) {
        const int srow_base = m0 + wm * 64 + mt * 16 + q * 4;
#pragma unroll
        for (int nt = 0; nt < 4; nt++) {
            const int d = wn * 64 + nt * 16 + m;
            float o[4];
            if (wn == 0) {          // d < 64 -> rope (pair in adjacent lane)
                const int jj = d >> 1;
#pragma unroll
                for (int r = 0; r < 4; r++) {
                    float x = acc[mt][nt][r];
                    float p = __shfl_xor(x, 1, 64);
                    float c = cosp[(srow_base + r) * HALF_DIM + jj];
                    float sn = sinp[(srow_base + r) * HALF_DIM + jj];
                    o[r] = (d & 1) ? (p * sn + x * c) : (x * c - p * sn);
                }
            } else {
#pragma unroll
                for (int r = 0; r < 4; r++) o[r] = acc[mt][nt][r];
            }
#pragma unroll
            for (int r = 0; r < 4; r++)
                ep[(wm * 64 + mt * 16 + q * 4 + r) * 136 + d] = f2bf(o[r]);
        }
    }
    __syncthreads();

#pragma unroll
    for (int u = 0; u < 8; u++) {
        int i = tid + u * 256;           // 2048 chunks of 16B
        int row = i >> 4, c8 = (i & 15) * 8;
        uint4 v = *(const uint4*)&ep[row * 136 + c8];
        *(uint4*)&Qo[((size_t)h * S_LEN + m0 + row) * HD_DIM + c8] = v;
    }
}

// ---------------------------------------------------------------------------
// Kernel 2: split-K GEMM for ktmp = x@wk (cols 0..127) and w = x@wproj (cols
// 128..191). 64x64 tile, BK=16. grid (32,3,7).
// ---------------------------------------------------------------------------
__global__ __launch_bounds__(256) void kw_gemm_kernel(
    const float* __restrict__ X, const float* __restrict__ WK,
    const float* __restrict__ WP, float* __restrict__ partial)
{
    __shared__ float Ast[16][64];
    __shared__ float Bs[16][64];
    const int tid = threadIdx.x;
    const int tx = tid & 15, ty = tid >> 4;
    const int m0 = blockIdx.x * 64;
    const int nt = blockIdx.y;
    const int kc = blockIdx.z;
    const float* Bp; int ldb, nbase;
    if (nt < 2) { Bp = WK; ldb = HD_DIM; nbase = nt * 64; }
    else        { Bp = WP; ldb = H_NUM; nbase = 0; }

    float acc[4][4];
#pragma unroll
    for (int i = 0; i < 4; i++)
#pragma unroll
        for (int j = 0; j < 4; j++) acc[i][j] = 0.f;

    const int arow = tid >> 2, ak = (tid & 3) * 4;
    const int brow = tid >> 4, bn = (tid & 15) * 4;
    const int kbeg = kc * KCHUNK_SZ;

    for (int kt = kbeg; kt < kbeg + KCHUNK_SZ; kt += 16) {
        float4 av = *(const float4*)&X[(size_t)(m0 + arow) * D_DIM + kt + ak];
        float4 bv = *(const float4*)&Bp[(size_t)(kt + brow) * ldb + nbase + bn];
        __syncthreads();
        Ast[ak + 0][arow] = av.x;
        Ast[ak + 1][arow] = av.y;
        Ast[ak + 2][arow] = av.z;
        Ast[ak + 3][arow] = av.w;
        *(float4*)&Bs[brow][bn] = bv;
        __syncthreads();
#pragma unroll
        for (int k = 0; k < 16; k++) {
            float4 a = *(const float4*)&Ast[k][ty * 4];
            float4 b = *(const float4*)&Bs[k][tx * 4];
            float aa[4] = {a.x, a.y, a.z, a.w};
            float bb[4] = {b.x, b.y, b.z, b.w};
#pragma unroll
            for (int i = 0; i < 4; i++)
#pragma unroll
                for (int j = 0; j < 4; j++)
                    acc[i][j] = fmaf(aa[i], bb[j], acc[i][j]);
        }
    }
    const int nc0 = nt * 64;
#pragma unroll
    for (int i = 0; i < 4; i++) {
        float4 v = {acc[i][0], acc[i][1], acc[i][2], acc[i][3]};
        *(float4*)&partial[((size_t)kc * S_LEN + m0 + ty * 4 + i) * 192 + nc0 + tx * 4] = v;
    }
}

__global__ __launch_bounds__(256) void kw_reduce_kernel(
    const float* __restrict__ partial, float* __restrict__ Ko, float* __restrict__ Wo)
{
    int g = blockIdx.x * 256 + threadIdx.x;   // < S*192
    int m = g / 192, n = g % 192;
    float s = 0.f;
#pragma unroll
    for (int c = 0; c < KCHUNKS; c++)
        s += partial[((size_t)c * S_LEN + m) * 192 + n];
    if (n < HD_DIM) Ko[(size_t)m * HD_DIM + n] = s;
    else            Wo[(size_t)m * H_NUM + (n - HD_DIM)] = s * W_SCALE;
}

// ---------------------------------------------------------------------------
// Kernel 3: per-row layernorm + interleaved RoPE on k; emits bf16 K.
// ---------------------------------------------------------------------------
__global__ __launch_bounds__(128) void knorm_rope_kernel(
    const float* __restrict__ Kf, const float* __restrict__ gw, const float* __restrict__ gb,
    const float* __restrict__ cosp, const float* __restrict__ sinp,
    ushort* __restrict__ Kbf)
{
    __shared__ float red[128];
    __shared__ float sh[128];
    const int m = blockIdx.x, t = threadIdx.x;
    float v = Kf[(size_t)m * HD_DIM + t];
    red[t] = v; __syncthreads();
    for (int off = 64; off > 0; off >>= 1) {
        if (t < off) red[t] += red[t + off];
        __syncthreads();
    }
    float mu = red[0] * (1.f / HD_DIM);
    __syncthreads();
    float dv = v - mu;
    red[t] = dv * dv; __syncthreads();
    for (int off = 64; off > 0; off >>= 1) {
        if (t < off) red[t] += red[t + off];
        __syncthreads();
    }
    float var = red[0] * (1.f / HD_DIM);
    float rs = rsqrtf(var + LN_EPS);
    float kn = dv * rs * gw[t] + gb[t];
    sh[t] = kn; __syncthreads();
    float out;
    if (t < ROPE_DIM) {
        int jj = t >> 1;
        float c = cosp[m * HALF_DIM + jj], sn = sinp[m * HALF_DIM + jj];
        out = ((t & 1) == 0) ? (sh[t] * c - sh[t + 1] * sn)
                             : (sh[t - 1] * sn + sh[t] * c);
    } else {
        out = kn;
    }
    Kbf[(size_t)m * HD_DIM + t] = f2bf(out);
}

// ---------------------------------------------------------------------------
// Kernel 4: index_score via bf16 MFMA. 64(s)x64(t) causal tiles, 528 blocks.
// ---------------------------------------------------------------------------
__global__ __launch_bounds__(256) void attn_mfma_kernel(
    const ushort* __restrict__ Qb,  // bf16 [H][S][HD]
    const ushort* __restrict__ Kb,  // bf16 [S][HD]
    const float* __restrict__ Wf,   // fp32 [S][H], pre-scaled
    float* __restrict__ SC)
{
    __shared__ ushort Ks[64 * 128];
    __shared__ ushort Qs[64 * 128];
    __shared__ float  Wsm[64 * 68];

    const int bidx = blockIdx.x;
    int ts = (int)((sqrtf(8.0f * bidx + 1.0f) - 1.0f) * 0.5f);
    while ((ts + 1) * (ts + 2) / 2 <= bidx) ts++;
    while (ts * (ts + 1) / 2 > bidx) ts--;
    const int tt = bidx - ts * (ts + 1) / 2;
    const int s0 = ts * 64, t0 = tt * 64;

    const int tid = threadIdx.x;
    const int lane = tid & 63;
    const int m = lane & 15;
    const int q = lane >> 4;
    const int strip = (tid >> 6) * 16;

    const int rb = tid >> 4;
    const int wblk = ((tid & 15) ^ rb) * 8;

    {
        const uint4* gk = (const uint4*)(Kb + (size_t)t0 * HD_DIM);
#pragma unroll
        for (int u = 0; u < 4; u++) {
            uint4 v = gk[tid + u * 256];
            *(uint4*)&Ks[(rb + u * 16) * 128 + wblk] = v;
        }
        const float4* gw = (const float4*)(Wf + (size_t)s0 * H_NUM);
#pragma unroll
        for (int u = 0; u < 4; u++) {
            int ch = tid + u * 256;
            float4 v = gw[ch];
            *(float4*)&Wsm[(ch >> 4) * 68 + (ch & 15) * 4] = v;
        }
    }
    __syncthreads();

    short8 bf[4][4];
#pragma unroll
    for (int tile = 0; tile < 4; tile++) {
        int row = tile * 16 + m;
#pragma unroll
        for (int ks = 0; ks < 4; ks++)
            bf[tile][ks] = *(const short8*)&Ks[row * 128 + (((ks << 2) + q) ^ m) * 8];
    }

    float acc[4][4];
#pragma unroll
    for (int tile = 0; tile < 4; tile++)
#pragma unroll
        for (int r = 0; r < 4; r++) acc[tile][r] = 0.f;

    for (int h = 0; h < H_NUM; h++) {
        uint4 v[4];
        const uint4* gq = (const uint4*)(Qb + ((size_t)h * S_LEN + s0) * HD_DIM);
#pragma unroll
        for (int u = 0; u < 4; u++) v[u] = gq[tid + u * 256];
        __syncthreads();
#pragma unroll
        for (int u = 0; u < 4; u++)
            *(uint4*)&Qs[(rb + u * 16) * 128 + wblk] = v[u];
        __syncthreads();

        short8 af[4];
        const int arow = strip + m;
#pragma unroll
        for (int ks = 0; ks < 4; ks++)
            af[ks] = *(const short8*)&Qs[arow * 128 + (((ks << 2) + q) ^ m) * 8];
        float wv[4];
#pragma unroll
        for (int r = 0; r < 4; r++) wv[r] = Wsm[(strip + q * 4 + r) * 68 + h];

#pragma unroll
        for (int tile = 0; tile < 4; tile++) {
            floatx4 p = {0.f, 0.f, 0.f, 0.f};
#pragma unroll
            for (int ks = 0; ks < 4; ks++)
                p = __builtin_amdgcn_mfma_f32_16x16x32_bf16(af[ks], bf[tile][ks], p, 0, 0, 0);
#pragma unroll
            for (int r = 0; r < 4; r++)
                acc[tile][r] += fmaxf(p[r], 0.f) * wv[r];
        }
    }

#pragma unroll
    for (int tile = 0; tile < 4; tile++)
#pragma unroll
        for (int r = 0; r < 4; r++)
            SC[(size_t)(s0 + strip + q * 4 + r) * S_LEN + t0 + tile * 16 + m] =
                acc[tile][r];
}

// ---------------------------------------------------------------------------
// Kernel 5: per-row top-512 via bitonic sort of 2048 packed u64 keys.
// ---------------------------------------------------------------------------
__device__ __forceinline__ unsigned int fkey(float f) {
    unsigned int u = __float_as_uint(f);
    return (u & 0x80000000u) ? ~u : (u | 0x80000000u);
}
__device__ __forceinline__ float fdec(unsigned int k) {
    unsigned int u = (k & 0x80000000u) ? (k & 0x7FFFFFFFu) : ~k;
    return __uint_as_float(u);
}

__global__ __launch_bounds__(256) void topk_kernel(
    const float* __restrict__ SC, float* __restrict__ outv, float* __restrict__ outi)
{
    __shared__ unsigned long long key[S_LEN];
    const int s = blockIdx.x, tid = threadIdx.x;
    for (int t = tid; t < S_LEN; t += 256) {
        float v = (t <= s) ? SC[(size_t)s * S_LEN + t] : NEG_INF_F;
        key[t] = ((unsigned long long)fkey(v) << 32) |
                 (unsigned long long)(unsigned int)(S_LEN - 1 - t);
    }
    __syncthreads();
    for (int k2 = 2; k2 <= S_LEN; k2 <<= 1) {
        for (int j = k2 >> 1; j > 0; j >>= 1) {
            for (int p = tid; p < S_LEN / 2; p += 256) {
                int i = 2 * p - (p & (j - 1));
                int ix = i + j;
                unsigned long long a = key[i], b = key[ix];
                bool up = ((i & k2) == 0);
                bool sw = up ? (a < b) : (a > b);
                if (sw) { key[i] = b; key[ix] = a; }
            }
            __syncthreads();
        }
    }
    for (int i2 = tid; i2 < TOPK_N; i2 += 256) {
        unsigned long long kv = key[i2];
        outv[(size_t)s * TOPK_N + i2] = fdec((unsigned int)(kv >> 32));
        outi[(size_t)s * TOPK_N + i2] =
            (float)(S_LEN - 1 - (int)(kv & 0xFFFFFFFFu));
    }
}

// ---------------------------------------------------------------------------
extern "C" void kernel_launch(void* const* d_in, const int* in_sizes, int n_in,
                              void* d_out, int out_size, void* d_ws, size_t ws_size,
                              hipStream_t stream)
{
    (void)in_sizes; (void)n_in; (void)out_size; (void)ws_size;
    const float* x      = (const float*)d_in[0];
    const float* q_lora = (const float*)d_in[1];
    const float* wq_b   = (const float*)d_in[2];
    const float* wk     = (const float*)d_in[3];
    const float* wproj  = (const float*)d_in[4];
    const float* knw    = (const float*)d_in[5];
    const float* knb    = (const float*)d_in[6];
    const float* cosp   = (const float*)d_in[7];
    const float* sinp   = (const float*)d_in[8];

    float* ws = (float*)d_ws;
    ushort* Qbf  = (ushort*)(ws + QBF_OFF);
    ushort* Albf = (ushort*)(ws + ALORA_OFF);
    ushort* WTbf = (ushort*)(ws + WT_OFF);
    float*  Kf   = ws + KF_OFF;
    ushort* Kbf  = (ushort*)(ws + KBF_OFF);
    float*  Wf   = ws + WF_OFF;
    float*  SCb  = ws + SC_OFF;
    float*  partial = ws + SC_OFF;   // alias: consumed before SC is written

    float* outv = (float*)d_out;
    float* outi = outv + (size_t)S_LEN * TOPK_N;

    cast_qlora_kernel<<<(S_LEN * QLR_DIM) / (256 * 8), 256, 0, stream>>>(q_lora, Albf);
    transpose_wqb_kernel<<<dim3(NQ_DIM / 64, QLR_DIM / 64), 256, 0, stream>>>(wq_b, WTbf);
    kw_gemm_kernel<<<dim3(S_LEN / 64, 3, KCHUNKS), 256, 0, stream>>>(
        x, wk, wproj, partial);
    kw_reduce_kernel<<<(S_LEN * 192) / 256, 256, 0, stream>>>(partial, Kf, Wf);
    knorm_rope_kernel<<<S_LEN, 128, 0, stream>>>(Kf, knw, knb, cosp, sinp, Kbf);
    qgemm_mfma_kernel<<<dim3(NQ_DIM / 128, S_LEN / 128), 256, 0, stream>>>(
        Albf, WTbf, cosp, sinp, Qbf);
    attn_mfma_kernel<<<528, 256, 0, stream>>>(Qbf, Kbf, Wf, SCb);
    topk_kernel<<<S_LEN, 256, 0, stream>>>(SCb, outv, outi);
}

// Round 4
// 501.637 us; speedup vs baseline: 4.2320x; 1.2400x over previous
//
#include <hip/hip_runtime.h>
#include <stdint.h>

#define S_LEN 2048
#define D_DIM 7168
#define H_NUM 64
#define HD_DIM 128
#define QLR_DIM 1536
#define NQ_DIM 8192      // H*HD
#define ROPE_DIM 64
#define HALF_DIM 32
#define TOPK_N 512
#define NEG_INF_F (-1e30f)
#define LN_EPS 1e-6f
#define W_SCALE 0.011048543456039806f   // 1/sqrt(64*128)

#define KCHUNKS 7
#define KCHUNK_SZ 1024

// workspace layout (float offsets)
#define QBF_OFF 0                                    // S*NQ bf16 = 8388608 floats
#define ALORA_OFF (QBF_OFF + S_LEN * NQ_DIM / 2)     // q_lora bf16: S*QLR/2
#define WT_OFF   (ALORA_OFF + S_LEN * QLR_DIM / 2)   // wq_b^T bf16: NQ*QLR/2
#define KF_OFF   (WT_OFF + NQ_DIM * QLR_DIM / 2)
#define KBF_OFF  (KF_OFF + S_LEN * HD_DIM)
#define WF_OFF   (KBF_OFF + S_LEN * HD_DIM / 2)
#define SC_OFF   (WF_OFF + S_LEN * H_NUM)            // scores S*S fp32
// split-K partials (7*S*192 = 2.75M floats) alias the score region (4.19M)

typedef __attribute__((ext_vector_type(8))) short short8;
typedef __attribute__((ext_vector_type(4))) float floatx4;

__device__ __forceinline__ ushort f2bf(float f) {
    unsigned int u = __float_as_uint(f);
    u += 0x7FFFu + ((u >> 16) & 1u);   // round-to-nearest-even
    return (ushort)(u >> 16);
}
__device__ __forceinline__ unsigned int pack2bf(float lo, float hi) {
    return (unsigned int)f2bf(lo) | ((unsigned int)f2bf(hi) << 16);
}

__device__ __forceinline__ void gld_lds16(const ushort* g, ushort* l) {
    __builtin_amdgcn_global_load_lds(
        (const __attribute__((address_space(1))) unsigned int*)g,
        (__attribute__((address_space(3))) unsigned int*)l, 16, 0, 0);
}

// ---------------------------------------------------------------------------
// Kernel 0a: cast q_lora fp32 -> bf16 [S][QLR]
// ---------------------------------------------------------------------------
__global__ __launch_bounds__(256) void cast_qlora_kernel(
    const float* __restrict__ in, ushort* __restrict__ out)
{
    int g = (blockIdx.x * 256 + threadIdx.x) * 8;
    float4 a = *(const float4*)&in[g];
    float4 b = *(const float4*)&in[g + 4];
    uint4 v;
    v.x = pack2bf(a.x, a.y); v.y = pack2bf(a.z, a.w);
    v.z = pack2bf(b.x, b.y); v.w = pack2bf(b.z, b.w);
    *(uint4*)&out[g] = v;
}

// ---------------------------------------------------------------------------
// Kernel 0b: transpose+cast wq_b fp32 [QLR][NQ] -> bf16 WT [NQ][QLR].
// ---------------------------------------------------------------------------
__global__ __launch_bounds__(256) void transpose_wqb_kernel(
    const float* __restrict__ W, ushort* __restrict__ WT)
{
    __shared__ ushort tl[64][72];
    const int n0 = blockIdx.x * 64, k0 = blockIdx.y * 64;
    const int t = threadIdx.x;
    const int r = t >> 4, c4 = (t & 15) * 4;
#pragma unroll
    for (int u = 0; u < 4; u++) {
        int kk = r + u * 16;
        float4 v = *(const float4*)&W[(size_t)(k0 + kk) * NQ_DIM + n0 + c4];
        tl[c4 + 0][kk] = f2bf(v.x);
        tl[c4 + 1][kk] = f2bf(v.y);
        tl[c4 + 2][kk] = f2bf(v.z);
        tl[c4 + 3][kk] = f2bf(v.w);
    }
    __syncthreads();
#pragma unroll
    for (int u = 0; u < 2; u++) {
        int i = t + u * 256;             // 512 chunks of 16B
        int nr = i >> 3, c8 = (i & 7) * 8;
        uint4 v = *(const uint4*)&tl[nr][c8];
        *(uint4*)&WT[(size_t)(n0 + nr) * QLR_DIM + k0 + c8] = v;
    }
}

// ---------------------------------------------------------------------------
// Kernel 1: Q = q_lora @ wq_b via bf16 MFMA (m97 structure). Fused RoPE
// epilogue, LDS-bounced coalesced store to [H][S][HD].
// ---------------------------------------------------------------------------
__global__ __launch_bounds__(256) void qgemm_mfma_kernel(
    const ushort* __restrict__ Abf,   // bf16 [S][QLR]
    const ushort* __restrict__ WT,    // bf16 [NQ][QLR]
    const float* __restrict__ cosp, const float* __restrict__ sinp,
    ushort* __restrict__ Qo)          // bf16 [H][S][HD]
{
    __shared__ ushort lds[128 * 136];          // staging aliases front
    ushort* As = lds;                          // 128 rows x 32 bf16 (64B rows)
    ushort* Bs = lds + 4096;                   // 128 rows x 32 bf16

    const int tid = threadIdx.x;
    const int lane = tid & 63;
    const int wave = tid >> 6;
    const int m = lane & 15;
    const int q = lane >> 4;
    const int wm = wave & 1, wn = wave >> 1;
    const int m0 = blockIdx.y * 128;
    const int n0 = blockIdx.x * 128;
    const int h = blockIdx.x;                  // 128 cols == one head

    floatx4 acc[4][4];
#pragma unroll
    for (int i = 0; i < 4; i++)
#pragma unroll
        for (int j = 0; j < 4; j++) acc[i][j] = (floatx4){0.f, 0.f, 0.f, 0.f};

    const ushort* agp[2];
    const ushort* bgp[2];
    unsigned int sbase[2];
#pragma unroll
    for (int u = 0; u < 2; u++) {
        int s = (u * 4 + wave) * 64 + lane;
        agp[u] = Abf + (size_t)(m0 + (s >> 2)) * QLR_DIM + (s & 3) * 8;
        bgp[u] = WT + (size_t)(n0 + (s >> 2)) * QLR_DIM + (s & 3) * 8;
        sbase[u] = (unsigned int)((u * 4 + wave) * 64 * 8);  // ushort offset
    }

    for (int kt = 0; kt < QLR_DIM; kt += 32) {
        __syncthreads();
#pragma unroll
        for (int u = 0; u < 2; u++) gld_lds16(agp[u] + kt, &As[sbase[u]]);
#pragma unroll
        for (int u = 0; u < 2; u++) gld_lds16(bgp[u] + kt, &Bs[sbase[u]]);
        __syncthreads();

        short8 af[4], bf[4];
#pragma unroll
        for (int mt = 0; mt < 4; mt++)
            af[mt] = *(const short8*)&As[(wm * 64 + mt * 16 + m) * 32 + q * 8];
#pragma unroll
        for (int nt = 0; nt < 4; nt++)
            bf[nt] = *(const short8*)&Bs[(wn * 64 + nt * 16 + m) * 32 + q * 8];
#pragma unroll
        for (int mt = 0; mt < 4; mt++)
#pragma unroll
            for (int nt = 0; nt < 4; nt++)
                acc[mt][nt] = __builtin_amdgcn_mfma_f32_16x16x32_bf16(
                    af[mt], bf[nt], acc[mt][nt], 0, 0, 0);
    }

    __syncthreads();
    ushort* ep = lds;  // 128 x (pitch 136) bf16

#pragma unroll
    for (int mt = 0; mt < 4; mt++) {
        const int srow_base = m0 + wm * 64 + mt * 16 + q * 4;
#pragma unroll
        for (int nt = 0; nt < 4; nt++) {
            const int d = wn * 64 + nt * 16 + m;
            float o[4];
            if (wn == 0) {          // d < 64 -> rope
                const int jj = d >> 1;
#pragma unroll
                for (int r = 0; r < 4; r++) {
                    float x = acc[mt][nt][r];
                    float p = __shfl_xor(x, 1, 64);
                    float c = cosp[(srow_base + r) * HALF_DIM + jj];
                    float sn = sinp[(srow_base + r) * HALF_DIM + jj];
                    o[r] = (d & 1) ? (p * sn + x * c) : (x * c - p * sn);
                }
            } else {
#pragma unroll
                for (int r = 0; r < 4; r++) o[r] = acc[mt][nt][r];
            }
#pragma unroll
            for (int r = 0; r < 4; r++)
                ep[(wm * 64 + mt * 16 + q * 4 + r) * 136 + d] = f2bf(o[r]);
        }
    }
    __syncthreads();

#pragma unroll
    for (int u = 0; u < 8; u++) {
        int i = tid + u * 256;           // 2048 chunks of 16B
        int row = i >> 4, c8 = (i & 15) * 8;
        uint4 v = *(const uint4*)&ep[row * 136 + c8];
        *(uint4*)&Qo[((size_t)h * S_LEN + m0 + row) * HD_DIM + c8] = v;
    }
}

// ---------------------------------------------------------------------------
// Kernel 2: split-K GEMM for ktmp = x@wk and w = x@wproj. grid (32,3,7).
// ---------------------------------------------------------------------------
__global__ __launch_bounds__(256) void kw_gemm_kernel(
    const float* __restrict__ X, const float* __restrict__ WK,
    const float* __restrict__ WP, float* __restrict__ partial)
{
    __shared__ float Ast[16][64];
    __shared__ float Bs[16][64];
    const int tid = threadIdx.x;
    const int tx = tid & 15, ty = tid >> 4;
    const int m0 = blockIdx.x * 64;
    const int nt = blockIdx.y;
    const int kc = blockIdx.z;
    const float* Bp; int ldb, nbase;
    if (nt < 2) { Bp = WK; ldb = HD_DIM; nbase = nt * 64; }
    else        { Bp = WP; ldb = H_NUM; nbase = 0; }

    float acc[4][4];
#pragma unroll
    for (int i = 0; i < 4; i++)
#pragma unroll
        for (int j = 0; j < 4; j++) acc[i][j] = 0.f;

    const int arow = tid >> 2, ak = (tid & 3) * 4;
    const int brow = tid >> 4, bn = (tid & 15) * 4;
    const int kbeg = kc * KCHUNK_SZ;

    for (int kt = kbeg; kt < kbeg + KCHUNK_SZ; kt += 16) {
        float4 av = *(const float4*)&X[(size_t)(m0 + arow) * D_DIM + kt + ak];
        float4 bv = *(const float4*)&Bp[(size_t)(kt + brow) * ldb + nbase + bn];
        __syncthreads();
        Ast[ak + 0][arow] = av.x;
        Ast[ak + 1][arow] = av.y;
        Ast[ak + 2][arow] = av.z;
        Ast[ak + 3][arow] = av.w;
        *(float4*)&Bs[brow][bn] = bv;
        __syncthreads();
#pragma unroll
        for (int k = 0; k < 16; k++) {
            float4 a = *(const float4*)&Ast[k][ty * 4];
            float4 b = *(const float4*)&Bs[k][tx * 4];
            float aa[4] = {a.x, a.y, a.z, a.w};
            float bb[4] = {b.x, b.y, b.z, b.w};
#pragma unroll
            for (int i = 0; i < 4; i++)
#pragma unroll
                for (int j = 0; j < 4; j++)
                    acc[i][j] = fmaf(aa[i], bb[j], acc[i][j]);
        }
    }
    const int nc0 = nt * 64;
#pragma unroll
    for (int i = 0; i < 4; i++) {
        float4 v = {acc[i][0], acc[i][1], acc[i][2], acc[i][3]};
        *(float4*)&partial[((size_t)kc * S_LEN + m0 + ty * 4 + i) * 192 + nc0 + tx * 4] = v;
    }
}

__global__ __launch_bounds__(256) void kw_reduce_kernel(
    const float* __restrict__ partial, float* __restrict__ Ko, float* __restrict__ Wo)
{
    int g = blockIdx.x * 256 + threadIdx.x;   // < S*192
    int m = g / 192, n = g % 192;
    float s = 0.f;
#pragma unroll
    for (int c = 0; c < KCHUNKS; c++)
        s += partial[((size_t)c * S_LEN + m) * 192 + n];
    if (n < HD_DIM) Ko[(size_t)m * HD_DIM + n] = s;
    else            Wo[(size_t)m * H_NUM + (n - HD_DIM)] = s * W_SCALE;
}

// ---------------------------------------------------------------------------
// Kernel 3: per-row layernorm + interleaved RoPE on k; emits bf16 K.
// ---------------------------------------------------------------------------
__global__ __launch_bounds__(128) void knorm_rope_kernel(
    const float* __restrict__ Kf, const float* __restrict__ gw, const float* __restrict__ gb,
    const float* __restrict__ cosp, const float* __restrict__ sinp,
    ushort* __restrict__ Kbf)
{
    __shared__ float red[128];
    __shared__ float sh[128];
    const int m = blockIdx.x, t = threadIdx.x;
    float v = Kf[(size_t)m * HD_DIM + t];
    red[t] = v; __syncthreads();
    for (int off = 64; off > 0; off >>= 1) {
        if (t < off) red[t] += red[t + off];
        __syncthreads();
    }
    float mu = red[0] * (1.f / HD_DIM);
    __syncthreads();
    float dv = v - mu;
    red[t] = dv * dv; __syncthreads();
    for (int off = 64; off > 0; off >>= 1) {
        if (t < off) red[t] += red[t + off];
        __syncthreads();
    }
    float var = red[0] * (1.f / HD_DIM);
    float rs = rsqrtf(var + LN_EPS);
    float kn = dv * rs * gw[t] + gb[t];
    sh[t] = kn; __syncthreads();
    float out;
    if (t < ROPE_DIM) {
        int jj = t >> 1;
        float c = cosp[m * HALF_DIM + jj], sn = sinp[m * HALF_DIM + jj];
        out = ((t & 1) == 0) ? (sh[t] * c - sh[t + 1] * sn)
                             : (sh[t - 1] * sn + sh[t] * c);
    } else {
        out = kn;
    }
    Kbf[(size_t)m * HD_DIM + t] = f2bf(out);
}

// ---------------------------------------------------------------------------
// Kernel 4: index_score via bf16 MFMA, barrier-free head loop.
// A (Q) and B (K) fragments loaded DIRECTLY from global (8 contiguous bf16
// per lane = one dwordx4); K frags resident in regs for the whole block;
// Q frags register double-buffered across heads. W in LDS (staged once).
// ---------------------------------------------------------------------------
__global__ __launch_bounds__(256) void attn_mfma_kernel(
    const ushort* __restrict__ Qb,  // bf16 [H][S][HD]
    const ushort* __restrict__ Kb,  // bf16 [S][HD]
    const float* __restrict__ Wf,   // fp32 [S][H], pre-scaled
    float* __restrict__ SC)
{
    __shared__ float Wsm[64 * 68];

    const int bidx = blockIdx.x;
    int ts = (int)((sqrtf(8.0f * bidx + 1.0f) - 1.0f) * 0.5f);
    while ((ts + 1) * (ts + 2) / 2 <= bidx) ts++;
    while (ts * (ts + 1) / 2 > bidx) ts--;
    const int tt = bidx - ts * (ts + 1) / 2;
    const int s0 = ts * 64, t0 = tt * 64;

    const int tid = threadIdx.x;
    const int lane = tid & 63;
    const int m = lane & 15;
    const int q = lane >> 4;
    const int strip = (tid >> 6) * 16;

    // ---- stage W tile (fp32) once ----
    {
        const float4* gw = (const float4*)(Wf + (size_t)s0 * H_NUM);
#pragma unroll
        for (int u = 0; u < 4; u++) {
            int ch = tid + u * 256;
            float4 v = gw[ch];
            *(float4*)&Wsm[(ch >> 4) * 68 + (ch & 15) * 4] = v;
        }
    }

    // ---- K B-fragments direct from global, resident all block ----
    short8 bf[4][4];   // [t-tile][k-step]
#pragma unroll
    for (int tile = 0; tile < 4; tile++)
#pragma unroll
        for (int ks = 0; ks < 4; ks++)
            bf[tile][ks] = *(const short8*)
                &Kb[(size_t)(t0 + tile * 16 + m) * HD_DIM + ks * 32 + q * 8];

    __syncthreads();   // Wsm ready (only barrier in the kernel)

    float acc[4][4];
#pragma unroll
    for (int tile = 0; tile < 4; tile++)
#pragma unroll
        for (int r = 0; r < 4; r++) acc[tile][r] = 0.f;

    // A-fragment base: row = s0+strip+m, col = q*8; per-head stride S*HD
    const ushort* qbase = Qb + (size_t)(s0 + strip + m) * HD_DIM + q * 8;
    const size_t hstride = (size_t)S_LEN * HD_DIM;
    const float* wrow = &Wsm[(strip + q * 4) * 68];

    short8 afA[4], afB[4];
#pragma unroll
    for (int ks = 0; ks < 4; ks++)
        afA[ks] = *(const short8*)&qbase[ks * 32];

    for (int h = 0; h < H_NUM; h += 2) {
        // prefetch h+1
#pragma unroll
        for (int ks = 0; ks < 4; ks++)
            afB[ks] = *(const short8*)&qbase[(size_t)(h + 1) * hstride + ks * 32];
        // compute h with afA
        {
            float wv[4];
#pragma unroll
            for (int r = 0; r < 4; r++) wv[r] = wrow[r * 68 + h];
#pragma unroll
            for (int tile = 0; tile < 4; tile++) {
                floatx4 p = {0.f, 0.f, 0.f, 0.f};
#pragma unroll
                for (int ks = 0; ks < 4; ks++)
                    p = __builtin_amdgcn_mfma_f32_16x16x32_bf16(afA[ks], bf[tile][ks], p, 0, 0, 0);
#pragma unroll
                for (int r = 0; r < 4; r++)
                    acc[tile][r] += fmaxf(p[r], 0.f) * wv[r];
            }
        }
        // prefetch h+2
        if (h + 2 < H_NUM) {
#pragma unroll
            for (int ks = 0; ks < 4; ks++)
                afA[ks] = *(const short8*)&qbase[(size_t)(h + 2) * hstride + ks * 32];
        }
        // compute h+1 with afB
        {
            float wv[4];
#pragma unroll
            for (int r = 0; r < 4; r++) wv[r] = wrow[r * 68 + h + 1];
#pragma unroll
            for (int tile = 0; tile < 4; tile++) {
                floatx4 p = {0.f, 0.f, 0.f, 0.f};
#pragma unroll
                for (int ks = 0; ks < 4; ks++)
                    p = __builtin_amdgcn_mfma_f32_16x16x32_bf16(afB[ks], bf[tile][ks], p, 0, 0, 0);
#pragma unroll
                for (int r = 0; r < 4; r++)
                    acc[tile][r] += fmaxf(p[r], 0.f) * wv[r];
            }
        }
    }

#pragma unroll
    for (int tile = 0; tile < 4; tile++)
#pragma unroll
        for (int r = 0; r < 4; r++)
            SC[(size_t)(s0 + strip + q * 4 + r) * S_LEN + t0 + tile * 16 + m] =
                acc[tile][r];
}

// ---------------------------------------------------------------------------
// Kernel 5: per-row top-512 via bitonic sort of 2048 packed u64 keys.
// ---------------------------------------------------------------------------
__device__ __forceinline__ unsigned int fkey(float f) {
    unsigned int u = __float_as_uint(f);
    return (u & 0x80000000u) ? ~u : (u | 0x80000000u);
}
__device__ __forceinline__ float fdec(unsigned int k) {
    unsigned int u = (k & 0x80000000u) ? (k & 0x7FFFFFFFu) : ~k;
    return __uint_as_float(u);
}

__global__ __launch_bounds__(256) void topk_kernel(
    const float* __restrict__ SC, float* __restrict__ outv, float* __restrict__ outi)
{
    __shared__ unsigned long long key[S_LEN];
    const int s = blockIdx.x, tid = threadIdx.x;
    for (int t = tid; t < S_LEN; t += 256) {
        float v = (t <= s) ? SC[(size_t)s * S_LEN + t] : NEG_INF_F;
        key[t] = ((unsigned long long)fkey(v) << 32) |
                 (unsigned long long)(unsigned int)(S_LEN - 1 - t);
    }
    __syncthreads();
    for (int k2 = 2; k2 <= S_LEN; k2 <<= 1) {
        for (int j = k2 >> 1; j > 0; j >>= 1) {
            for (int p = tid; p < S_LEN / 2; p += 256) {
                int i = 2 * p - (p & (j - 1));
                int ix = i + j;
                unsigned long long a = key[i], b = key[ix];
                bool up = ((i & k2) == 0);
                bool sw = up ? (a < b) : (a > b);
                if (sw) { key[i] = b; key[ix] = a; }
            }
            __syncthreads();
        }
    }
    for (int i2 = tid; i2 < TOPK_N; i2 += 256) {
        unsigned long long kv = key[i2];
        outv[(size_t)s * TOPK_N + i2] = fdec((unsigned int)(kv >> 32));
        outi[(size_t)s * TOPK_N + i2] =
            (float)(S_LEN - 1 - (int)(kv & 0xFFFFFFFFu));
    }
}

// ---------------------------------------------------------------------------
extern "C" void kernel_launch(void* const* d_in, const int* in_sizes, int n_in,
                              void* d_out, int out_size, void* d_ws, size_t ws_size,
                              hipStream_t stream)
{
    (void)in_sizes; (void)n_in; (void)out_size; (void)ws_size;
    const float* x      = (const float*)d_in[0];
    const float* q_lora = (const float*)d_in[1];
    const float* wq_b   = (const float*)d_in[2];
    const float* wk     = (const float*)d_in[3];
    const float* wproj  = (const float*)d_in[4];
    const float* knw    = (const float*)d_in[5];
    const float* knb    = (const float*)d_in[6];
    const float* cosp   = (const float*)d_in[7];
    const float* sinp   = (const float*)d_in[8];

    float* ws = (float*)d_ws;
    ushort* Qbf  = (ushort*)(ws + QBF_OFF);
    ushort* Albf = (ushort*)(ws + ALORA_OFF);
    ushort* WTbf = (ushort*)(ws + WT_OFF);
    float*  Kf   = ws + KF_OFF;
    ushort* Kbf  = (ushort*)(ws + KBF_OFF);
    float*  Wf   = ws + WF_OFF;
    float*  SCb  = ws + SC_OFF;
    float*  partial = ws + SC_OFF;   // alias: consumed before SC is written

    float* outv = (float*)d_out;
    float* outi = outv + (size_t)S_LEN * TOPK_N;

    cast_qlora_kernel<<<(S_LEN * QLR_DIM) / (256 * 8), 256, 0, stream>>>(q_lora, Albf);
    transpose_wqb_kernel<<<dim3(NQ_DIM / 64, QLR_DIM / 64), 256, 0, stream>>>(wq_b, WTbf);
    kw_gemm_kernel<<<dim3(S_LEN / 64, 3, KCHUNKS), 256, 0, stream>>>(
        x, wk, wproj, partial);
    kw_reduce_kernel<<<(S_LEN * 192) / 256, 256, 0, stream>>>(partial, Kf, Wf);
    knorm_rope_kernel<<<S_LEN, 128, 0, stream>>>(Kf, knw, knb, cosp, sinp, Kbf);
    qgemm_mfma_kernel<<<dim3(NQ_DIM / 128, S_LEN / 128), 256, 0, stream>>>(
        Albf, WTbf, cosp, sinp, Qbf);
    attn_mfma_kernel<<<528, 256, 0, stream>>>(Qbf, Kbf, Wf, SCb);
    topk_kernel<<<S_LEN, 256, 0, stream>>>(SCb, outv, outi);
}

// Round 5
// 450.328 us; speedup vs baseline: 4.7142x; 1.1139x over previous
//
#include <hip/hip_runtime.h>
#include <stdint.h>

#define S_LEN 2048
#define D_DIM 7168
#define H_NUM 64
#define HD_DIM 128
#define QLR_DIM 1536
#define NQ_DIM 8192      // H*HD
#define ROPE_DIM 64
#define HALF_DIM 32
#define TOPK_N 512
#define NEG_INF_F (-1e30f)
#define LN_EPS 1e-6f
#define W_SCALE 0.011048543456039806f   // 1/sqrt(64*128)

#define KCHUNKS 7
#define KCHUNK_SZ 1024

// workspace layout (float offsets)
#define QBF_OFF 0                                    // S*NQ bf16 = 8388608 floats
#define ALORA_OFF (QBF_OFF + S_LEN * NQ_DIM / 2)     // q_lora bf16
#define WT_OFF   (ALORA_OFF + S_LEN * QLR_DIM / 2)   // wq_b^T bf16
#define XBF_OFF  (WT_OFF + NQ_DIM * QLR_DIM / 2)     // x bf16: S*D/2 floats
#define WT2_OFF  (XBF_OFF + S_LEN * D_DIM / 2)       // [wk|wproj]^T bf16: 192*D/2
#define KF_OFF   (WT2_OFF + 192 * D_DIM / 2)
#define KBF_OFF  (KF_OFF + S_LEN * HD_DIM)
#define WF_OFF   (KBF_OFF + S_LEN * HD_DIM / 2)
#define SC_OFF   (WF_OFF + S_LEN * H_NUM)            // scores S*S fp32
// split-K partials (7*S*192 = 2.75M floats) alias the score region (4.19M)

typedef __attribute__((ext_vector_type(8))) short short8;
typedef __attribute__((ext_vector_type(4))) float floatx4;

__device__ __forceinline__ ushort f2bf(float f) {
    unsigned int u = __float_as_uint(f);
    u += 0x7FFFu + ((u >> 16) & 1u);   // round-to-nearest-even
    return (ushort)(u >> 16);
}
__device__ __forceinline__ unsigned int pack2bf(float lo, float hi) {
    return (unsigned int)f2bf(lo) | ((unsigned int)f2bf(hi) << 16);
}

__device__ __forceinline__ void gld_lds16(const ushort* g, ushort* l) {
    __builtin_amdgcn_global_load_lds(
        (const __attribute__((address_space(1))) unsigned int*)g,
        (__attribute__((address_space(3))) unsigned int*)l, 16, 0, 0);
}

// ---------------------------------------------------------------------------
// Kernel 0a: generic fp32 -> bf16 cast (8 elems/thread)
// ---------------------------------------------------------------------------
__global__ __launch_bounds__(256) void cast_bf16_kernel(
    const float* __restrict__ in, ushort* __restrict__ out)
{
    int g = (blockIdx.x * 256 + threadIdx.x) * 8;
    float4 a = *(const float4*)&in[g];
    float4 b = *(const float4*)&in[g + 4];
    uint4 v;
    v.x = pack2bf(a.x, a.y); v.y = pack2bf(a.z, a.w);
    v.z = pack2bf(b.x, b.y); v.w = pack2bf(b.z, b.w);
    *(uint4*)&out[g] = v;
}

// ---------------------------------------------------------------------------
// Kernel 0b: transpose+cast wq_b fp32 [QLR][NQ] -> bf16 WT [NQ][QLR].
// ---------------------------------------------------------------------------
__global__ __launch_bounds__(256) void transpose_wqb_kernel(
    const float* __restrict__ W, ushort* __restrict__ WT)
{
    __shared__ ushort tl[64][72];
    const int n0 = blockIdx.x * 64, k0 = blockIdx.y * 64;
    const int t = threadIdx.x;
    const int r = t >> 4, c4 = (t & 15) * 4;
#pragma unroll
    for (int u = 0; u < 4; u++) {
        int kk = r + u * 16;
        float4 v = *(const float4*)&W[(size_t)(k0 + kk) * NQ_DIM + n0 + c4];
        tl[c4 + 0][kk] = f2bf(v.x);
        tl[c4 + 1][kk] = f2bf(v.y);
        tl[c4 + 2][kk] = f2bf(v.z);
        tl[c4 + 3][kk] = f2bf(v.w);
    }
    __syncthreads();
#pragma unroll
    for (int u = 0; u < 2; u++) {
        int i = t + u * 256;             // 512 chunks of 16B
        int nr = i >> 3, c8 = (i & 7) * 8;
        uint4 v = *(const uint4*)&tl[nr][c8];
        *(uint4*)&WT[(size_t)(n0 + nr) * QLR_DIM + k0 + c8] = v;
    }
}

// ---------------------------------------------------------------------------
// Kernel 0c: transpose+cast [wk | wproj] -> bf16 WT2 [192][D].
// n-tile 0,1: wk cols; n-tile 2: wproj cols. grid (3, D/64).
// ---------------------------------------------------------------------------
__global__ __launch_bounds__(256) void transpose_wkp_kernel(
    const float* __restrict__ WK, const float* __restrict__ WP,
    ushort* __restrict__ WT2)
{
    __shared__ ushort tl[64][72];
    const int ntile = blockIdx.x;
    const int k0 = blockIdx.y * 64;
    const float* src; int ld, cbase;
    if (ntile < 2) { src = WK; ld = HD_DIM; cbase = ntile * 64; }
    else           { src = WP; ld = H_NUM; cbase = 0; }
    const int t = threadIdx.x;
    const int r = t >> 4, c4 = (t & 15) * 4;
#pragma unroll
    for (int u = 0; u < 4; u++) {
        int kk = r + u * 16;
        float4 v = *(const float4*)&src[(size_t)(k0 + kk) * ld + cbase + c4];
        tl[c4 + 0][kk] = f2bf(v.x);
        tl[c4 + 1][kk] = f2bf(v.y);
        tl[c4 + 2][kk] = f2bf(v.z);
        tl[c4 + 3][kk] = f2bf(v.w);
    }
    __syncthreads();
#pragma unroll
    for (int u = 0; u < 2; u++) {
        int i = t + u * 256;
        int nr = i >> 3, c8 = (i & 7) * 8;
        uint4 v = *(const uint4*)&tl[nr][c8];
        *(uint4*)&WT2[(size_t)(ntile * 64 + nr) * D_DIM + k0 + c8] = v;
    }
}

// ---------------------------------------------------------------------------
// Kernel 1: Q = q_lora @ wq_b via bf16 MFMA (m97 structure). Fused RoPE
// epilogue, LDS-bounced coalesced store to [H][S][HD].
// ---------------------------------------------------------------------------
__global__ __launch_bounds__(256) void qgemm_mfma_kernel(
    const ushort* __restrict__ Abf,   // bf16 [S][QLR]
    const ushort* __restrict__ WT,    // bf16 [NQ][QLR]
    const float* __restrict__ cosp, const float* __restrict__ sinp,
    ushort* __restrict__ Qo)          // bf16 [H][S][HD]
{
    __shared__ ushort lds[128 * 136];          // staging aliases front
    ushort* As = lds;                          // 128 rows x 32 bf16
    ushort* Bs = lds + 4096;

    const int tid = threadIdx.x;
    const int lane = tid & 63;
    const int wave = tid >> 6;
    const int m = lane & 15;
    const int q = lane >> 4;
    const int wm = wave & 1, wn = wave >> 1;
    const int m0 = blockIdx.y * 128;
    const int n0 = blockIdx.x * 128;
    const int h = blockIdx.x;

    floatx4 acc[4][4];
#pragma unroll
    for (int i = 0; i < 4; i++)
#pragma unroll
        for (int j = 0; j < 4; j++) acc[i][j] = (floatx4){0.f, 0.f, 0.f, 0.f};

    const ushort* agp[2];
    const ushort* bgp[2];
    unsigned int sbase[2];
#pragma unroll
    for (int u = 0; u < 2; u++) {
        int s = (u * 4 + wave) * 64 + lane;
        agp[u] = Abf + (size_t)(m0 + (s >> 2)) * QLR_DIM + (s & 3) * 8;
        bgp[u] = WT + (size_t)(n0 + (s >> 2)) * QLR_DIM + (s & 3) * 8;
        sbase[u] = (unsigned int)((u * 4 + wave) * 64 * 8);
    }

    for (int kt = 0; kt < QLR_DIM; kt += 32) {
        __syncthreads();
#pragma unroll
        for (int u = 0; u < 2; u++) gld_lds16(agp[u] + kt, &As[sbase[u]]);
#pragma unroll
        for (int u = 0; u < 2; u++) gld_lds16(bgp[u] + kt, &Bs[sbase[u]]);
        __syncthreads();

        short8 af[4], bf[4];
#pragma unroll
        for (int mt = 0; mt < 4; mt++)
            af[mt] = *(const short8*)&As[(wm * 64 + mt * 16 + m) * 32 + q * 8];
#pragma unroll
        for (int nt = 0; nt < 4; nt++)
            bf[nt] = *(const short8*)&Bs[(wn * 64 + nt * 16 + m) * 32 + q * 8];
#pragma unroll
        for (int mt = 0; mt < 4; mt++)
#pragma unroll
            for (int nt = 0; nt < 4; nt++)
                acc[mt][nt] = __builtin_amdgcn_mfma_f32_16x16x32_bf16(
                    af[mt], bf[nt], acc[mt][nt], 0, 0, 0);
    }

    __syncthreads();
    ushort* ep = lds;  // 128 x (pitch 136) bf16

#pragma unroll
    for (int mt = 0; mt < 4; mt++) {
        const int srow_base = m0 + wm * 64 + mt * 16 + q * 4;
#pragma unroll
        for (int nt = 0; nt < 4; nt++) {
            const int d = wn * 64 + nt * 16 + m;
            float o[4];
            if (wn == 0) {          // d < 64 -> rope
                const int jj = d >> 1;
#pragma unroll
                for (int r = 0; r < 4; r++) {
                    float x = acc[mt][nt][r];
                    float p = __shfl_xor(x, 1, 64);
                    float c = cosp[(srow_base + r) * HALF_DIM + jj];
                    float sn = sinp[(srow_base + r) * HALF_DIM + jj];
                    o[r] = (d & 1) ? (p * sn + x * c) : (x * c - p * sn);
                }
            } else {
#pragma unroll
                for (int r = 0; r < 4; r++) o[r] = acc[mt][nt][r];
            }
#pragma unroll
            for (int r = 0; r < 4; r++)
                ep[(wm * 64 + mt * 16 + q * 4 + r) * 136 + d] = f2bf(o[r]);
        }
    }
    __syncthreads();

#pragma unroll
    for (int u = 0; u < 8; u++) {
        int i = tid + u * 256;
        int row = i >> 4, c8 = (i & 15) * 8;
        uint4 v = *(const uint4*)&ep[row * 136 + c8];
        *(uint4*)&Qo[((size_t)h * S_LEN + m0 + row) * HD_DIM + c8] = v;
    }
}

// ---------------------------------------------------------------------------
// Kernel 2: [ktmp|w] = x @ [wk|wproj] via bf16 MFMA, split-K.
// 128(M)x64(N) tile, BK=64, grid (16,3,7). global_load_lds staging with
// source-index XOR swizzle (kblk ^ row&7) -> conflict-free frag reads.
// ---------------------------------------------------------------------------
__global__ __launch_bounds__(256) void kw_mfma_kernel(
    const ushort* __restrict__ Xbf,   // bf16 [S][D]
    const ushort* __restrict__ WT2,   // bf16 [192][D]
    float* __restrict__ partial)      // [kc][S][192]
{
    __shared__ ushort As[128 * 64];   // 16 KB
    __shared__ ushort Bs[64 * 64];    //  8 KB

    const int tid = threadIdx.x;
    const int lane = tid & 63;
    const int wave = tid >> 6;
    const int m = lane & 15;
    const int q = lane >> 4;
    const int wm = wave & 1, wn = wave >> 1;
    const int m0 = blockIdx.x * 128;
    const int n0 = blockIdx.y * 64;
    const int kc = blockIdx.z;
    const size_t kbase = (size_t)kc * KCHUNK_SZ;

    // staging pointers: slot s covers LDS 16B chunk s; row=s>>3, c=s&7,
    // global kblk = c ^ (row&7)
    const ushort* agp[4];
    unsigned int abase[4];
#pragma unroll
    for (int u = 0; u < 4; u++) {
        int s = (u * 4 + wave) * 64 + lane;
        int row = s >> 3, c = s & 7;
        int kg = c ^ (row & 7);
        agp[u] = Xbf + (size_t)(m0 + row) * D_DIM + kbase + kg * 8;
        abase[u] = (unsigned int)((u * 4 + wave) * 64 * 8);
    }
    const ushort* bgp[2];
    unsigned int bbase[2];
#pragma unroll
    for (int u = 0; u < 2; u++) {
        int s = (u * 4 + wave) * 64 + lane;
        int row = s >> 3, c = s & 7;
        int kg = c ^ (row & 7);
        bgp[u] = WT2 + (size_t)(n0 + row) * D_DIM + kbase + kg * 8;
        bbase[u] = (unsigned int)((u * 4 + wave) * 64 * 8);
    }

    floatx4 acc[4][2];
#pragma unroll
    for (int i = 0; i < 4; i++)
#pragma unroll
        for (int j = 0; j < 2; j++) acc[i][j] = (floatx4){0.f, 0.f, 0.f, 0.f};

    for (int kt = 0; kt < KCHUNK_SZ; kt += 64) {
        __syncthreads();
#pragma unroll
        for (int u = 0; u < 4; u++) gld_lds16(agp[u] + kt, &As[abase[u]]);
#pragma unroll
        for (int u = 0; u < 2; u++) gld_lds16(bgp[u] + kt, &Bs[bbase[u]]);
        __syncthreads();

        short8 af[4][2], bfr[2][2];
#pragma unroll
        for (int mt = 0; mt < 4; mt++) {
            int row = wm * 64 + mt * 16 + m;
#pragma unroll
            for (int ks = 0; ks < 2; ks++)
                af[mt][ks] = *(const short8*)
                    &As[row * 64 + ((((ks << 2) + q) ^ (m & 7)) * 8)];
        }
#pragma unroll
        for (int nt = 0; nt < 2; nt++) {
            int row = wn * 32 + nt * 16 + m;
#pragma unroll
            for (int ks = 0; ks < 2; ks++)
                bfr[nt][ks] = *(const short8*)
                    &Bs[row * 64 + ((((ks << 2) + q) ^ (m & 7)) * 8)];
        }
#pragma unroll
        for (int mt = 0; mt < 4; mt++)
#pragma unroll
            for (int nt = 0; nt < 2; nt++)
#pragma unroll
                for (int ks = 0; ks < 2; ks++)
                    acc[mt][nt] = __builtin_amdgcn_mfma_f32_16x16x32_bf16(
                        af[mt][ks], bfr[nt][ks], acc[mt][nt], 0, 0, 0);
    }

#pragma unroll
    for (int mt = 0; mt < 4; mt++) {
        int grow = m0 + wm * 64 + mt * 16 + q * 4;
#pragma unroll
        for (int nt = 0; nt < 2; nt++) {
            int gn = n0 + wn * 32 + nt * 16 + m;
#pragma unroll
            for (int r = 0; r < 4; r++)
                partial[((size_t)kc * S_LEN + grow + r) * 192 + gn] = acc[mt][nt][r];
        }
    }
}

__global__ __launch_bounds__(256) void kw_reduce_kernel(
    const float* __restrict__ partial, float* __restrict__ Ko, float* __restrict__ Wo)
{
    int g = blockIdx.x * 256 + threadIdx.x;   // < S*192
    int m = g / 192, n = g % 192;
    float s = 0.f;
#pragma unroll
    for (int c = 0; c < KCHUNKS; c++)
        s += partial[((size_t)c * S_LEN + m) * 192 + n];
    if (n < HD_DIM) Ko[(size_t)m * HD_DIM + n] = s;
    else            Wo[(size_t)m * H_NUM + (n - HD_DIM)] = s * W_SCALE;
}

// ---------------------------------------------------------------------------
// Kernel 3: per-row layernorm + interleaved RoPE on k; emits bf16 K.
// ---------------------------------------------------------------------------
__global__ __launch_bounds__(128) void knorm_rope_kernel(
    const float* __restrict__ Kf, const float* __restrict__ gw, const float* __restrict__ gb,
    const float* __restrict__ cosp, const float* __restrict__ sinp,
    ushort* __restrict__ Kbf)
{
    __shared__ float red[128];
    __shared__ float sh[128];
    const int m = blockIdx.x, t = threadIdx.x;
    float v = Kf[(size_t)m * HD_DIM + t];
    red[t] = v; __syncthreads();
    for (int off = 64; off > 0; off >>= 1) {
        if (t < off) red[t] += red[t + off];
        __syncthreads();
    }
    float mu = red[0] * (1.f / HD_DIM);
    __syncthreads();
    float dv = v - mu;
    red[t] = dv * dv; __syncthreads();
    for (int off = 64; off > 0; off >>= 1) {
        if (t < off) red[t] += red[t + off];
        __syncthreads();
    }
    float var = red[0] * (1.f / HD_DIM);
    float rs = rsqrtf(var + LN_EPS);
    float kn = dv * rs * gw[t] + gb[t];
    sh[t] = kn; __syncthreads();
    float out;
    if (t < ROPE_DIM) {
        int jj = t >> 1;
        float c = cosp[m * HALF_DIM + jj], sn = sinp[m * HALF_DIM + jj];
        out = ((t & 1) == 0) ? (sh[t] * c - sh[t + 1] * sn)
                             : (sh[t - 1] * sn + sh[t] * c);
    } else {
        out = kn;
    }
    Kbf[(size_t)m * HD_DIM + t] = f2bf(out);
}

// ---------------------------------------------------------------------------
// Kernel 4: index_score via bf16 MFMA, barrier-free head loop.
// ---------------------------------------------------------------------------
__global__ __launch_bounds__(256) void attn_mfma_kernel(
    const ushort* __restrict__ Qb,  // bf16 [H][S][HD]
    const ushort* __restrict__ Kb,  // bf16 [S][HD]
    const float* __restrict__ Wf,   // fp32 [S][H], pre-scaled
    float* __restrict__ SC)
{
    __shared__ float Wsm[64 * 68];

    const int bidx = blockIdx.x;
    int ts = (int)((sqrtf(8.0f * bidx + 1.0f) - 1.0f) * 0.5f);
    while ((ts + 1) * (ts + 2) / 2 <= bidx) ts++;
    while (ts * (ts + 1) / 2 > bidx) ts--;
    const int tt = bidx - ts * (ts + 1) / 2;
    const int s0 = ts * 64, t0 = tt * 64;

    const int tid = threadIdx.x;
    const int lane = tid & 63;
    const int m = lane & 15;
    const int q = lane >> 4;
    const int strip = (tid >> 6) * 16;

    {
        const float4* gw = (const float4*)(Wf + (size_t)s0 * H_NUM);
#pragma unroll
        for (int u = 0; u < 4; u++) {
            int ch = tid + u * 256;
            float4 v = gw[ch];
            *(float4*)&Wsm[(ch >> 4) * 68 + (ch & 15) * 4] = v;
        }
    }

    short8 bf[4][4];   // [t-tile][k-step]
#pragma unroll
    for (int tile = 0; tile < 4; tile++)
#pragma unroll
        for (int ks = 0; ks < 4; ks++)
            bf[tile][ks] = *(const short8*)
                &Kb[(size_t)(t0 + tile * 16 + m) * HD_DIM + ks * 32 + q * 8];

    __syncthreads();   // Wsm ready

    float acc[4][4];
#pragma unroll
    for (int tile = 0; tile < 4; tile++)
#pragma unroll
        for (int r = 0; r < 4; r++) acc[tile][r] = 0.f;

    const ushort* qbase = Qb + (size_t)(s0 + strip + m) * HD_DIM + q * 8;
    const size_t hstride = (size_t)S_LEN * HD_DIM;
    const float* wrow = &Wsm[(strip + q * 4) * 68];

    short8 afA[4], afB[4];
#pragma unroll
    for (int ks = 0; ks < 4; ks++)
        afA[ks] = *(const short8*)&qbase[ks * 32];

    for (int h = 0; h < H_NUM; h += 2) {
#pragma unroll
        for (int ks = 0; ks < 4; ks++)
            afB[ks] = *(const short8*)&qbase[(size_t)(h + 1) * hstride + ks * 32];
        {
            float wv[4];
#pragma unroll
            for (int r = 0; r < 4; r++) wv[r] = wrow[r * 68 + h];
#pragma unroll
            for (int tile = 0; tile < 4; tile++) {
                floatx4 p = {0.f, 0.f, 0.f, 0.f};
#pragma unroll
                for (int ks = 0; ks < 4; ks++)
                    p = __builtin_amdgcn_mfma_f32_16x16x32_bf16(afA[ks], bf[tile][ks], p, 0, 0, 0);
#pragma unroll
                for (int r = 0; r < 4; r++)
                    acc[tile][r] += fmaxf(p[r], 0.f) * wv[r];
            }
        }
        if (h + 2 < H_NUM) {
#pragma unroll
            for (int ks = 0; ks < 4; ks++)
                afA[ks] = *(const short8*)&qbase[(size_t)(h + 2) * hstride + ks * 32];
        }
        {
            float wv[4];
#pragma unroll
            for (int r = 0; r < 4; r++) wv[r] = wrow[r * 68 + h + 1];
#pragma unroll
            for (int tile = 0; tile < 4; tile++) {
                floatx4 p = {0.f, 0.f, 0.f, 0.f};
#pragma unroll
                for (int ks = 0; ks < 4; ks++)
                    p = __builtin_amdgcn_mfma_f32_16x16x32_bf16(afB[ks], bf[tile][ks], p, 0, 0, 0);
#pragma unroll
                for (int r = 0; r < 4; r++)
                    acc[tile][r] += fmaxf(p[r], 0.f) * wv[r];
            }
        }
    }

#pragma unroll
    for (int tile = 0; tile < 4; tile++)
#pragma unroll
        for (int r = 0; r < 4; r++)
            SC[(size_t)(s0 + strip + q * 4 + r) * S_LEN + t0 + tile * 16 + m] =
                acc[tile][r];
}

// ---------------------------------------------------------------------------
// Kernel 5: per-row top-512 via bitonic sort of 2048 packed u64 keys.
// ---------------------------------------------------------------------------
__device__ __forceinline__ unsigned int fkey(float f) {
    unsigned int u = __float_as_uint(f);
    return (u & 0x80000000u) ? ~u : (u | 0x80000000u);
}
__device__ __forceinline__ float fdec(unsigned int k) {
    unsigned int u = (k & 0x80000000u) ? (k & 0x7FFFFFFFu) : ~k;
    return __uint_as_float(u);
}

__global__ __launch_bounds__(256) void topk_kernel(
    const float* __restrict__ SC, float* __restrict__ outv, float* __restrict__ outi)
{
    __shared__ unsigned long long key[S_LEN];
    const int s = blockIdx.x, tid = threadIdx.x;
    for (int t = tid; t < S_LEN; t += 256) {
        float v = (t <= s) ? SC[(size_t)s * S_LEN + t] : NEG_INF_F;
        key[t] = ((unsigned long long)fkey(v) << 32) |
                 (unsigned long long)(unsigned int)(S_LEN - 1 - t);
    }
    __syncthreads();
    for (int k2 = 2; k2 <= S_LEN; k2 <<= 1) {
        for (int j = k2 >> 1; j > 0; j >>= 1) {
            for (int p = tid; p < S_LEN / 2; p += 256) {
                int i = 2 * p - (p & (j - 1));
                int ix = i + j;
                unsigned long long a = key[i], b = key[ix];
                bool up = ((i & k2) == 0);
                bool sw = up ? (a < b) : (a > b);
                if (sw) { key[i] = b; key[ix] = a; }
            }
            __syncthreads();
        }
    }
    for (int i2 = tid; i2 < TOPK_N; i2 += 256) {
        unsigned long long kv = key[i2];
        outv[(size_t)s * TOPK_N + i2] = fdec((unsigned int)(kv >> 32));
        outi[(size_t)s * TOPK_N + i2] =
            (float)(S_LEN - 1 - (int)(kv & 0xFFFFFFFFu));
    }
}

// ---------------------------------------------------------------------------
extern "C" void kernel_launch(void* const* d_in, const int* in_sizes, int n_in,
                              void* d_out, int out_size, void* d_ws, size_t ws_size,
                              hipStream_t stream)
{
    (void)in_sizes; (void)n_in; (void)out_size; (void)ws_size;
    const float* x      = (const float*)d_in[0];
    const float* q_lora = (const float*)d_in[1];
    const float* wq_b   = (const float*)d_in[2];
    const float* wk     = (const float*)d_in[3];
    const float* wproj  = (const float*)d_in[4];
    const float* knw    = (const float*)d_in[5];
    const float* knb    = (const float*)d_in[6];
    const float* cosp   = (const float*)d_in[7];
    const float* sinp   = (const float*)d_in[8];

    float* ws = (float*)d_ws;
    ushort* Qbf  = (ushort*)(ws + QBF_OFF);
    ushort* Albf = (ushort*)(ws + ALORA_OFF);
    ushort* WTbf = (ushort*)(ws + WT_OFF);
    ushort* Xbf  = (ushort*)(ws + XBF_OFF);
    ushort* WT2  = (ushort*)(ws + WT2_OFF);
    float*  Kf   = ws + KF_OFF;
    ushort* Kbf  = (ushort*)(ws + KBF_OFF);
    float*  Wf   = ws + WF_OFF;
    float*  SCb  = ws + SC_OFF;
    float*  partial = ws + SC_OFF;   // alias: consumed before SC is written

    float* outv = (float*)d_out;
    float* outi = outv + (size_t)S_LEN * TOPK_N;

    cast_bf16_kernel<<<(S_LEN * QLR_DIM) / (256 * 8), 256, 0, stream>>>(q_lora, Albf);
    cast_bf16_kernel<<<(S_LEN * D_DIM) / (256 * 8), 256, 0, stream>>>(x, Xbf);
    transpose_wqb_kernel<<<dim3(NQ_DIM / 64, QLR_DIM / 64), 256, 0, stream>>>(wq_b, WTbf);
    transpose_wkp_kernel<<<dim3(3, D_DIM / 64), 256, 0, stream>>>(wk, wproj, WT2);
    kw_mfma_kernel<<<dim3(S_LEN / 128, 3, KCHUNKS), 256, 0, stream>>>(Xbf, WT2, partial);
    kw_reduce_kernel<<<(S_LEN * 192) / 256, 256, 0, stream>>>(partial, Kf, Wf);
    knorm_rope_kernel<<<S_LEN, 128, 0, stream>>>(Kf, knw, knb, cosp, sinp, Kbf);
    qgemm_mfma_kernel<<<dim3(NQ_DIM / 128, S_LEN / 128), 256, 0, stream>>>(
        Albf, WTbf, cosp, sinp, Qbf);
    attn_mfma_kernel<<<528, 256, 0, stream>>>(Qbf, Kbf, Wf, SCb);
    topk_kernel<<<S_LEN, 256, 0, stream>>>(SCb, outv, outi);
}